// Round 4
// baseline (1762.284 us; speedup 1.0000x reference)
//
#include <hip/hip_runtime.h>
#include <cstdint>
#include <cstddef>

#define N_AREA 10000
#define N_FEAT 16
#define HID 64
#define BATCH 64
#define EPSL 1e-5f
#define SLOPE 0.01f
#define NCHUNK 157  // ceil(10000/64)

typedef int iv4 __attribute__((ext_vector_type(4)));
typedef int iv2 __attribute__((ext_vector_type(2)));
typedef float fv4 __attribute__((ext_vector_type(4)));

__device__ __forceinline__ float lrelu(float x) { return x >= 0.f ? x : SLOPE * x; }
__device__ __forceinline__ float tanh_fast(float x) {
    float t = __expf(2.0f * x);  // v_exp_f32 path
    return 1.0f - 2.0f / (t + 1.0f);
}

__global__ __launch_bounds__(256) void k_zero(int* p, int n) {
    int i = blockIdx.x * 256 + threadIdx.x;
    if (i < n) p[i] = 0;
}

__global__ __launch_bounds__(256) void k_hist(const int* __restrict__ dst, int* __restrict__ counts, int E) {
    int e = blockIdx.x * 256 + threadIdx.x;
    if (e < E) atomicAdd(&counts[dst[e]], 1);
}

// offsets (exclusive, padded to x4 per node: 1 self-loop + real edges + weight-0 pads),
// dinv, self-loop entry, pad entries, cursor init.
__global__ __launch_bounds__(1024) void k_scan(const int* __restrict__ counts, int* __restrict__ offsets,
                                               int* __restrict__ cursor, float* __restrict__ dinv,
                                               int2* __restrict__ ew) {
    const int PER = 10;
    int t = threadIdx.x;
    int base = t * PER;
    int local[PER];
    int sum = 0;
#pragma unroll
    for (int i = 0; i < PER; ++i) {
        int idx = base + i;
        int c = (idx < N_AREA) ? (((counts[idx] + 1) + 3) & ~3) : 0;  // padded count
        local[i] = sum;
        sum += c;
    }
    __shared__ int part[1024];
    part[t] = sum;
    __syncthreads();
    for (int off = 1; off < 1024; off <<= 1) {
        int v = (t >= off) ? part[t - off] : 0;
        __syncthreads();
        part[t] += v;
        __syncthreads();
    }
    int excl = (t == 0) ? 0 : part[t - 1];
    if (t == 1023) offsets[N_AREA] = part[1023];
    for (int i = 0; i < PER; ++i) {
        int idx = base + i;
        if (idx < N_AREA) {
            int off = excl + local[i];
            offsets[idx] = off;
            int c = counts[idx] + 1;          // real count (self + edges)
            int pc = (c + 3) & ~3;            // padded
            float dv = rsqrtf((float)c);
            dinv[idx] = dv;
            ew[off] = make_int2(idx, __float_as_int(dv * dv));  // self loop
            for (int pp = c; pp < pc; ++pp) ew[off + pp] = make_int2(idx, 0);  // weight-0 pads
            cursor[idx] = off + 1;
        }
    }
}

__global__ __launch_bounds__(256) void k_scatter(const int* __restrict__ ei, const float* __restrict__ dinv,
                                                 int* __restrict__ cursor, int2* __restrict__ ew, int E) {
    int e = blockIdx.x * 256 + threadIdx.x;
    if (e < E) {
        int s = ei[e], d = ei[E + e];
        int p = atomicAdd(&cursor[d], 1);
        ew[p] = make_int2(s, __float_as_int(dinv[s] * dinv[d]));
    }
}

// conv1 fused: gather(state rows of 16) -> @W1+b1 -> LN -> leaky -> h1 [B][N][64]
__global__ __launch_bounds__(256, 8) void k_conv1(const float* __restrict__ state, const float* __restrict__ W1,
                                                  const float* __restrict__ b1, const float* __restrict__ g1,
                                                  const float* __restrict__ be1, float* __restrict__ h1,
                                                  const int* __restrict__ offs, const int2* __restrict__ ew) {
    __shared__ float xs[64][20];  // padded: node stride 20 floats keeps b128 aligned + banks spread
    __shared__ float ws[16][64];
    int blk = blockIdx.x;
    int xc = blk & 7, ii = blk >> 3;  // XCD group: batch b on XCD b%8
    int b = xc + 8 * (ii / NCHUNK);
    int c = ii % NCHUNK;
    int n0 = c * 64;
    int t = threadIdx.x;
    *(float4*)&ws[t >> 4][(t & 15) * 4] = *(const float4*)(W1 + (t >> 4) * HID + (t & 15) * 4);
    int ln = t >> 2, q = t & 3;
    int n = n0 + ln;
    const float* sb = state + (size_t)b * (N_AREA * N_FEAT);
    float4 acc = make_float4(0.f, 0.f, 0.f, 0.f);
    if (n < N_AREA) {
        int beg = offs[n], end = offs[n + 1];
        for (int e = beg; e < end; ++e) {
            int2 sw = ew[e];
            float w = __int_as_float(sw.y);
            float4 v = *(const float4*)(sb + (size_t)sw.x * N_FEAT + q * 4);
            acc.x += w * v.x; acc.y += w * v.y; acc.z += w * v.z; acc.w += w * v.w;
        }
    }
    *(float4*)&xs[ln][q * 4] = acc;
    __syncthreads();
    int wave = t >> 6, lane = t & 63;
    float bias = b1[lane], gg = g1[lane], bb = be1[lane];
    for (int j = 0; j < 16; ++j) {
        int lnn = wave * 16 + j;
        float a = bias;
#pragma unroll
        for (int f = 0; f < N_FEAT; ++f) a += xs[lnn][f] * ws[f][lane];
        float s = a;
#pragma unroll
        for (int m = 1; m < 64; m <<= 1) s += __shfl_xor(s, m);
        float mu = s * (1.0f / 64.0f);
        float dv = a - mu;
        float qv = dv * dv;
#pragma unroll
        for (int m = 1; m < 64; m <<= 1) qv += __shfl_xor(qv, m);
        float rstd = rsqrtf(qv * (1.0f / 64.0f) + EPSL);
        float y = lrelu(dv * rstd * gg + bb);
        int nn = n0 + lnn;
        if (nn < N_AREA) h1[(size_t)b * (N_AREA * HID) + (size_t)nn * HID + lane] = y;
    }
}

// Fused conv: deep-MLP quad gather -> 64x64 GEMM -> epilogue.
// 4 blocks/CU forced via 33 KB LDS: 128 concurrent blocks/XCD < 157 chunks -> one 2.56 MB
// batch slice resident per XCD L2. Streaming traffic (edges, out, EPI2 resid) is nt so it
// doesn't evict the slice.
// a_t uses granule-XOR swizzle: phys col granule = (n>>2) ^ ((k>>2)&7)  (write 8-way -> 2-way).
// EPI 0: out = leaky(.+b) + resid
// EPI 2: h3 = leaky(LN(.+b)) + resid; out = tanh(h3 @ Wf + bf)
template <int EPI>
__global__ __launch_bounds__(256, 4) void k_conv(const float* __restrict__ src, const float* __restrict__ W,
                                                 const float* __restrict__ bias, const float* __restrict__ g,
                                                 const float* __restrict__ be, const float* __restrict__ resid,
                                                 float* __restrict__ out, const int* __restrict__ offs,
                                                 const int2* __restrict__ ew, const float* __restrict__ Wf,
                                                 const float* __restrict__ bf) {
    __shared__ float a_t[64][132];  // 33792 B -> exactly 4 blocks/CU; 132 % 32 == 4 (same bank math as 68)
    int blk = blockIdx.x;
    int xc = blk & 7, ii = blk >> 3;
    int b = xc + 8 * (ii / NCHUNK);
    int c = ii % NCHUNK;
    int n0 = c * 64;
    int t = threadIdx.x;
    int lane = t & 63;
    int wave = __builtin_amdgcn_readfirstlane(t) >> 6;  // provably wave-uniform
    int q = lane >> 4;         // quad group 0..3
    int ql = lane & 15;
    int f4 = ql * 4;           // feature sub-offset within the row
    const float* sb = src + (size_t)b * (N_AREA * HID);
    int nb = n0 + wave * 16;   // first node of this wave (uniform)
    int beg = (nb < N_AREA) ? offs[nb] : 0;
    for (int j = 0; j < 16; ++j) {
        int n = nb + j;  // uniform
        fv4 a0 = {0.f, 0.f, 0.f, 0.f}, a1 = a0, a2 = a0, a3 = a0;
        if (n < N_AREA) {
            int end = offs[n + 1];  // scalar; beg chained from previous node
            int e = beg;
#pragma unroll 2
            for (; e + 15 < end; e += 16) {  // 16 edges: 4 independent row-load chains
                iv4 E0 = __builtin_nontemporal_load((const iv4*)&ew[e + 2 * q]);      // edges e+2q, e+2q+1
                iv4 E1 = __builtin_nontemporal_load((const iv4*)&ew[e + 8 + 2 * q]);  // edges e+8+2q, +1
                fv4 v0 = *(const fv4*)(sb + (unsigned)E0.x * HID + f4);
                fv4 v1 = *(const fv4*)(sb + (unsigned)E0.z * HID + f4);
                fv4 v2 = *(const fv4*)(sb + (unsigned)E1.x * HID + f4);
                fv4 v3 = *(const fv4*)(sb + (unsigned)E1.z * HID + f4);
                float w0 = __int_as_float(E0.y), w1 = __int_as_float(E0.w);
                float w2 = __int_as_float(E1.y), w3 = __int_as_float(E1.w);
                a0 += w0 * v0; a1 += w1 * v1; a2 += w2 * v2; a3 += w3 * v3;
            }
            for (; e < end; e += 4) {  // padded x4: 4-edge tail quads
                iv2 ea = __builtin_nontemporal_load((const iv2*)&ew[e + q]);
                fv4 va = *(const fv4*)(sb + (unsigned)ea.x * HID + f4);
                a0 += __int_as_float(ea.y) * va;
            }
            beg = end;
        }
        // merge 4 chains, then reduce across quads (lanes L, L^16, L^32, L^48 share features)
        fv4 acc = (a0 + a1) + (a2 + a3);
        acc.x += __shfl_xor(acc.x, 16); acc.y += __shfl_xor(acc.y, 16);
        acc.z += __shfl_xor(acc.z, 16); acc.w += __shfl_xor(acc.w, 16);
        acc.x += __shfl_xor(acc.x, 32); acc.y += __shfl_xor(acc.y, 32);
        acc.z += __shfl_xor(acc.z, 32); acc.w += __shfl_xor(acc.w, 32);
        if (q == 0) {
            int ln = wave * 16 + j;
            // swizzled store: rows f4..f4+3 (k>>2 == ql), phys granule = (ln>>2) ^ (ql&7)
            int colp = 4 * ((ln >> 2) ^ (ql & 7)) + (ln & 3);
            a_t[f4 + 0][colp] = acc.x;
            a_t[f4 + 1][colp] = acc.y;
            a_t[f4 + 2][colp] = acc.z;
            a_t[f4 + 3][colp] = acc.w;
        }
    }
    __syncthreads();
    int ty = t >> 4, tx = t & 15;
    int r0 = ty * 4, c0 = tx * 4;
    float am[4][4] = {};
#pragma unroll 4
    for (int k = 0; k < 64; ++k) {
        fv4 av = *(const fv4*)&a_t[k][4 * (ty ^ ((k >> 2) & 7))];  // inverse swizzle -> logical nodes r0..r0+3
        fv4 wv = *(const fv4*)(W + k * HID + c0);  // 16 KB, L1-resident, shared by all blocks
        am[0][0] += av.x * wv.x; am[0][1] += av.x * wv.y; am[0][2] += av.x * wv.z; am[0][3] += av.x * wv.w;
        am[1][0] += av.y * wv.x; am[1][1] += av.y * wv.y; am[1][2] += av.y * wv.z; am[1][3] += av.y * wv.w;
        am[2][0] += av.z * wv.x; am[2][1] += av.z * wv.y; am[2][2] += av.z * wv.z; am[2][3] += av.z * wv.w;
        am[3][0] += av.w * wv.x; am[3][1] += av.w * wv.y; am[3][2] += av.w * wv.z; am[3][3] += av.w * wv.w;
    }
    float4 bv = *(const float4*)(bias + c0);
#pragma unroll
    for (int i = 0; i < 4; ++i) {
        am[i][0] += bv.x; am[i][1] += bv.y; am[i][2] += bv.z; am[i][3] += bv.w;
    }
    if constexpr (EPI >= 1) {  // LayerNorm across 64 feats (feats live on the 16-thread tx group)
        float4 gv = *(const float4*)(g + c0);
        float4 bev = *(const float4*)(be + c0);
        float gg[4] = {gv.x, gv.y, gv.z, gv.w};
        float bb[4] = {bev.x, bev.y, bev.z, bev.w};
#pragma unroll
        for (int i = 0; i < 4; ++i) {
            float s = am[i][0] + am[i][1] + am[i][2] + am[i][3];
            float qv = am[i][0] * am[i][0] + am[i][1] * am[i][1] + am[i][2] * am[i][2] + am[i][3] * am[i][3];
#pragma unroll
            for (int m = 1; m < 16; m <<= 1) {
                s += __shfl_xor(s, m);
                qv += __shfl_xor(qv, m);
            }
            float mu = s * (1.0f / 64.0f);
            float var = qv * (1.0f / 64.0f) - mu * mu;
            float rstd = rsqrtf(var + EPSL);
#pragma unroll
            for (int j = 0; j < 4; ++j) am[i][j] = (am[i][j] - mu) * rstd * gg[j] + bb[j];
        }
    }
    const float* rb = resid + (size_t)b * (N_AREA * HID);
    float* ob = out + (size_t)b * (N_AREA * HID);
    if constexpr (EPI == 0) {
#pragma unroll
        for (int i = 0; i < 4; ++i) {
            int n = n0 + r0 + i;
            if (n < N_AREA) {
                // resid == src slice here: normal load (L2-hit, keep resident)
                float4 rv = *(const float4*)(rb + (size_t)n * HID + c0);
                fv4 o;
                o.x = lrelu(am[i][0]) + rv.x;
                o.y = lrelu(am[i][1]) + rv.y;
                o.z = lrelu(am[i][2]) + rv.z;
                o.w = lrelu(am[i][3]) + rv.w;
                __builtin_nontemporal_store(o, (fv4*)(ob + (size_t)n * HID + c0));
            }
        }
    } else {  // EPI == 2: finish h3 in-register, stash tile to LDS, GEMM2 with Wf, tanh, store
#pragma unroll
        for (int i = 0; i < 4; ++i) {
            int n = n0 + r0 + i;
            int nc = n < N_AREA ? n : (N_AREA - 1);  // clamp OOB rows (values unused)
            // resid (h1) is a different array than src slice: stream it, don't pollute L2
            fv4 rv = __builtin_nontemporal_load((const fv4*)(rb + (size_t)nc * HID + c0));
            am[i][0] = lrelu(am[i][0]) + rv.x;
            am[i][1] = lrelu(am[i][1]) + rv.y;
            am[i][2] = lrelu(am[i][2]) + rv.z;
            am[i][3] = lrelu(am[i][3]) + rv.w;
        }
        __syncthreads();  // all GEMM1 reads of a_t done
        float (*h3s)[132] = a_t;  // reuse as [node][feat], plain indexing
#pragma unroll
        for (int i = 0; i < 4; ++i)
            *(float4*)&h3s[r0 + i][c0] = make_float4(am[i][0], am[i][1], am[i][2], am[i][3]);
        __syncthreads();
#pragma unroll
        for (int i = 0; i < 4; ++i) { am[i][0] = 0.f; am[i][1] = 0.f; am[i][2] = 0.f; am[i][3] = 0.f; }
#pragma unroll 4
        for (int k = 0; k < 64; ++k) {
            fv4 wv = *(const fv4*)(Wf + k * HID + c0);
            float a0 = h3s[r0 + 0][k];  // 16 distinct addrs per wave, 4-lane broadcast
            float a1 = h3s[r0 + 1][k];
            float a2 = h3s[r0 + 2][k];
            float a3 = h3s[r0 + 3][k];
            am[0][0] += a0 * wv.x; am[0][1] += a0 * wv.y; am[0][2] += a0 * wv.z; am[0][3] += a0 * wv.w;
            am[1][0] += a1 * wv.x; am[1][1] += a1 * wv.y; am[1][2] += a1 * wv.z; am[1][3] += a1 * wv.w;
            am[2][0] += a2 * wv.x; am[2][1] += a2 * wv.y; am[2][2] += a2 * wv.z; am[2][3] += a2 * wv.w;
            am[3][0] += a3 * wv.x; am[3][1] += a3 * wv.y; am[3][2] += a3 * wv.z; am[3][3] += a3 * wv.w;
        }
        float4 bfv = *(const float4*)(bf + c0);
#pragma unroll
        for (int i = 0; i < 4; ++i) {
            int n = n0 + r0 + i;
            if (n < N_AREA) {
                fv4 o;
                o.x = tanh_fast(am[i][0] + bfv.x);
                o.y = tanh_fast(am[i][1] + bfv.y);
                o.z = tanh_fast(am[i][2] + bfv.z);
                o.w = tanh_fast(am[i][3] + bfv.w);
                __builtin_nontemporal_store(o, (fv4*)(ob + (size_t)n * HID + c0));
            }
        }
    }
}

extern "C" void kernel_launch(void* const* d_in, const int* in_sizes, int n_in,
                              void* d_out, int out_size, void* d_ws, size_t ws_size,
                              hipStream_t stream) {
    const float* state = (const float*)d_in[0];
    const int* ei = (const int*)d_in[1];
    const int E = in_sizes[1] / 2;
    const float* W1 = (const float*)d_in[5];
    const float* b1 = (const float*)d_in[6];
    const float* W2 = (const float*)d_in[7];
    const float* b2 = (const float*)d_in[8];
    const float* W3 = (const float*)d_in[9];
    const float* b3 = (const float*)d_in[10];
    const float* g1 = (const float*)d_in[11];
    const float* be1 = (const float*)d_in[12];
    const float* g3 = (const float*)d_in[13];
    const float* be3 = (const float*)d_in[14];
    const float* Wf = (const float*)d_in[15];
    const float* bf = (const float*)d_in[16];
    float* out = (float*)d_out;

    uint8_t* base = (uint8_t*)d_ws;
    size_t off = 0;
    auto carve = [&](size_t bytes) {
        void* p = base + off;
        off = (off + bytes + 255) & ~(size_t)255;
        return p;
    };
    float* dinv = (float*)carve(N_AREA * 4);
    int* counts = (int*)carve(N_AREA * 4);
    int* offsets = (int*)carve((N_AREA + 1) * 4);
    int* cursor = (int*)carve(N_AREA * 4);
    int2* ew = (int2*)carve(((size_t)E + 4 * N_AREA) * 8);  // padded edge list
    float* h1 = (float*)carve((size_t)BATCH * N_AREA * HID * 4);
    float* h2 = (float*)carve((size_t)BATCH * N_AREA * HID * 4);

    const int GRID = 8 * NCHUNK * (BATCH / 8);  // 10048

    k_zero<<<(N_AREA + 255) / 256, 256, 0, stream>>>(counts, N_AREA);
    k_hist<<<(E + 255) / 256, 256, 0, stream>>>(ei + E, counts, E);
    k_scan<<<1, 1024, 0, stream>>>(counts, offsets, cursor, dinv, ew);
    k_scatter<<<(E + 255) / 256, 256, 0, stream>>>(ei, dinv, cursor, ew, E);

    k_conv1<<<GRID, 256, 0, stream>>>(state, W1, b1, g1, be1, h1, offsets, ew);
    k_conv<0><<<GRID, 256, 0, stream>>>(h1, W2, b2, nullptr, nullptr, h1, h2, offsets, ew, nullptr, nullptr);
    k_conv<2><<<GRID, 256, 0, stream>>>(h2, W3, b3, g3, be3, h1, out, offsets, ew, Wf, bf);
}

// Round 5
// 1411.708 us; speedup vs baseline: 1.2483x; 1.2483x over previous
//
#include <hip/hip_runtime.h>
#include <hip/hip_fp16.h>
#include <cstdint>
#include <cstddef>

#define N_AREA 10000
#define N_FEAT 16
#define HID 64
#define BATCH 64
#define EPSL 1e-5f
#define SLOPE 0.01f
#define NCHUNK 157  // ceil(10000/64)

__device__ __forceinline__ float lrelu(float x) { return x >= 0.f ? x : SLOPE * x; }
__device__ __forceinline__ float tanh_fast(float x) {
    float t = __expf(2.0f * x);  // v_exp_f32 path
    return 1.0f - 2.0f / (t + 1.0f);
}
__device__ __forceinline__ float2 h2f2(unsigned u) {
    return __half22float2(*reinterpret_cast<const __half2*>(&u));
}
__device__ __forceinline__ unsigned f2h2(float a, float b) {
    __half2 h = __floats2half2_rn(a, b);
    return *reinterpret_cast<const unsigned*>(&h);
}

__global__ __launch_bounds__(256) void k_zero(int* p, int n) {
    int i = blockIdx.x * 256 + threadIdx.x;
    if (i < n) p[i] = 0;
}

__global__ __launch_bounds__(256) void k_hist(const int* __restrict__ dst, int* __restrict__ counts, int E) {
    int e = blockIdx.x * 256 + threadIdx.x;
    if (e < E) atomicAdd(&counts[dst[e]], 1);
}

// offsets (exclusive, padded to x4 per node: 1 self-loop + real edges + weight-0 pads),
// dinv, self-loop entry, pad entries, cursor init.
__global__ __launch_bounds__(1024) void k_scan(const int* __restrict__ counts, int* __restrict__ offsets,
                                               int* __restrict__ cursor, float* __restrict__ dinv,
                                               int2* __restrict__ ew) {
    const int PER = 10;
    int t = threadIdx.x;
    int base = t * PER;
    int local[PER];
    int sum = 0;
#pragma unroll
    for (int i = 0; i < PER; ++i) {
        int idx = base + i;
        int c = (idx < N_AREA) ? (((counts[idx] + 1) + 3) & ~3) : 0;  // padded count
        local[i] = sum;
        sum += c;
    }
    __shared__ int part[1024];
    part[t] = sum;
    __syncthreads();
    for (int off = 1; off < 1024; off <<= 1) {
        int v = (t >= off) ? part[t - off] : 0;
        __syncthreads();
        part[t] += v;
        __syncthreads();
    }
    int excl = (t == 0) ? 0 : part[t - 1];
    if (t == 1023) offsets[N_AREA] = part[1023];
    for (int i = 0; i < PER; ++i) {
        int idx = base + i;
        if (idx < N_AREA) {
            int off = excl + local[i];
            offsets[idx] = off;
            int c = counts[idx] + 1;          // real count (self + edges)
            int pc = (c + 3) & ~3;            // padded
            float dv = rsqrtf((float)c);
            dinv[idx] = dv;
            ew[off] = make_int2(idx, __float_as_int(dv * dv));  // self loop
            for (int pp = c; pp < pc; ++pp) ew[off + pp] = make_int2(idx, 0);  // weight-0 pads
            cursor[idx] = off + 1;
        }
    }
}

__global__ __launch_bounds__(256) void k_scatter(const int* __restrict__ ei, const float* __restrict__ dinv,
                                                 int* __restrict__ cursor, int2* __restrict__ ew, int E) {
    int e = blockIdx.x * 256 + threadIdx.x;
    if (e < E) {
        int s = ei[e], d = ei[E + e];
        int p = atomicAdd(&cursor[d], 1);
        ew[p] = make_int2(s, __float_as_int(dinv[s] * dinv[d]));
    }
}

// conv1 fused: gather(state rows of 16) -> @W1+b1 -> LN -> leaky -> h1 (fp16) [B][N][64]
__global__ __launch_bounds__(256, 8) void k_conv1(const float* __restrict__ state, const float* __restrict__ W1,
                                                  const float* __restrict__ b1, const float* __restrict__ g1,
                                                  const float* __restrict__ be1, unsigned short* __restrict__ h1,
                                                  const int* __restrict__ offs, const int2* __restrict__ ew) {
    __shared__ float xs[64][20];  // padded: node stride 20 floats keeps b128 aligned + banks spread
    __shared__ float ws[16][64];
    int blk = blockIdx.x;
    int xc = blk & 7, ii = blk >> 3;  // XCD group: batch b on XCD b%8
    int b = xc + 8 * (ii / NCHUNK);
    int c = ii % NCHUNK;
    int n0 = c * 64;
    int t = threadIdx.x;
    *(float4*)&ws[t >> 4][(t & 15) * 4] = *(const float4*)(W1 + (t >> 4) * HID + (t & 15) * 4);
    int ln = t >> 2, q = t & 3;
    int n = n0 + ln;
    const float* sb = state + (size_t)b * (N_AREA * N_FEAT);
    float4 acc = make_float4(0.f, 0.f, 0.f, 0.f);
    if (n < N_AREA) {
        int beg = offs[n], end = offs[n + 1];
        for (int e = beg; e < end; ++e) {
            int2 sw = ew[e];
            float w = __int_as_float(sw.y);
            float4 v = *(const float4*)(sb + (size_t)sw.x * N_FEAT + q * 4);
            acc.x += w * v.x; acc.y += w * v.y; acc.z += w * v.z; acc.w += w * v.w;
        }
    }
    *(float4*)&xs[ln][q * 4] = acc;
    __syncthreads();
    int wave = t >> 6, lane = t & 63;
    float bias = b1[lane], gg = g1[lane], bb = be1[lane];
    for (int j = 0; j < 16; ++j) {
        int lnn = wave * 16 + j;
        float a = bias;
#pragma unroll
        for (int f = 0; f < N_FEAT; ++f) a += xs[lnn][f] * ws[f][lane];
        float s = a;
#pragma unroll
        for (int m = 1; m < 64; m <<= 1) s += __shfl_xor(s, m);
        float mu = s * (1.0f / 64.0f);
        float dv = a - mu;
        float qv = dv * dv;
#pragma unroll
        for (int m = 1; m < 64; m <<= 1) qv += __shfl_xor(qv, m);
        float rstd = rsqrtf(qv * (1.0f / 64.0f) + EPSL);
        float y = lrelu(dv * rstd * gg + bb);
        int nn = n0 + lnn;
        // pack lane pairs -> one 4B store per even lane (h1 is fp16)
        unsigned hv = (unsigned)__half_as_ushort(__float2half_rn(y));
        unsigned ov = (unsigned)__shfl_xor((int)hv, 1);
        if (((lane & 1) == 0) && nn < N_AREA)
            *(unsigned*)(h1 + (size_t)b * (N_AREA * HID) + (size_t)nn * HID + lane) = hv | (ov << 16);
    }
}

// Fused conv over fp16 h: quad-edge gather (16 lanes x 8B per 128B row, 4 edges/instr)
//  -> 64x64 GEMM (fp32 acc) -> epilogue.
// EPI 0: h2(fp16) = leaky(.+b) + resid(fp16 h1)
// EPI 2: h3 = leaky(LN(.+b)) + resid; out(fp32) = tanh(h3 @ Wf + bf)
template <int EPI>
__global__ __launch_bounds__(256, 8) void k_conv(const unsigned short* __restrict__ src, const float* __restrict__ W,
                                                 const float* __restrict__ bias, const float* __restrict__ g,
                                                 const float* __restrict__ be, const unsigned short* __restrict__ resid,
                                                 void* __restrict__ out, const int* __restrict__ offs,
                                                 const int2* __restrict__ ew, const float* __restrict__ Wf,
                                                 const float* __restrict__ bf) {
    __shared__ float a_t[64][68];  // [feat][node] for GEMM1; reused as [node][feat] for fused GEMM2
    int blk = blockIdx.x;
    int xc = blk & 7, ii = blk >> 3;
    int b = xc + 8 * (ii / NCHUNK);
    int c = ii % NCHUNK;
    int n0 = c * 64;
    int t = threadIdx.x;
    int lane = t & 63;
    int wave = __builtin_amdgcn_readfirstlane(t) >> 6;  // provably wave-uniform -> scalar offs/e
    int q = lane >> 4;        // which edge of the quad this lane handles
    int f4 = (lane & 15) * 4; // feature sub-offset within the row (4 halves per lane)
    const unsigned short* sb = src + (size_t)b * (N_AREA * HID);
    int nb = n0 + wave * 16;  // first node of this wave (uniform)
    int beg = (nb < N_AREA) ? offs[nb] : 0;
    for (int j = 0; j < 16; ++j) {
        int n = nb + j;  // uniform
        float4 acc = make_float4(0.f, 0.f, 0.f, 0.f);
        float4 acc2 = make_float4(0.f, 0.f, 0.f, 0.f);
        if (n < N_AREA) {
            int end = offs[n + 1];  // scalar; beg chained from previous node
            int e = beg;
            for (; e + 7 < end; e += 8) {  // 2 independent quads (8 edges) in flight
                int2 ea = ew[e + q];
                int2 eb = ew[e + 4 + q];
                uint2 ra = *(const uint2*)(sb + (unsigned)ea.x * HID + f4);  // 4 halves
                uint2 rb2 = *(const uint2*)(sb + (unsigned)eb.x * HID + f4);
                float wa = __int_as_float(ea.y), wb = __int_as_float(eb.y);
                float2 a01 = h2f2(ra.x), a23 = h2f2(ra.y);
                float2 b01 = h2f2(rb2.x), b23 = h2f2(rb2.y);
                acc.x += wa * a01.x; acc.y += wa * a01.y; acc.z += wa * a23.x; acc.w += wa * a23.y;
                acc2.x += wb * b01.x; acc2.y += wb * b01.y; acc2.z += wb * b23.x; acc2.w += wb * b23.y;
            }
            for (; e < end; e += 4) {  // padded x4: at most one remainder quad
                int2 ea = ew[e + q];
                uint2 ra = *(const uint2*)(sb + (unsigned)ea.x * HID + f4);
                float wa = __int_as_float(ea.y);
                float2 a01 = h2f2(ra.x), a23 = h2f2(ra.y);
                acc.x += wa * a01.x; acc.y += wa * a01.y; acc.z += wa * a23.x; acc.w += wa * a23.y;
            }
            beg = end;
        }
        // reduce the 4 quad-partials (lanes L, L^16, L^32, L^48 hold same features)
        acc.x += acc2.x; acc.y += acc2.y; acc.z += acc2.z; acc.w += acc2.w;
        acc.x += __shfl_xor(acc.x, 16); acc.y += __shfl_xor(acc.y, 16);
        acc.z += __shfl_xor(acc.z, 16); acc.w += __shfl_xor(acc.w, 16);
        acc.x += __shfl_xor(acc.x, 32); acc.y += __shfl_xor(acc.y, 32);
        acc.z += __shfl_xor(acc.z, 32); acc.w += __shfl_xor(acc.w, 32);
        if (q == 0) {
            int ln = wave * 16 + j;
            a_t[f4 + 0][ln] = acc.x;
            a_t[f4 + 1][ln] = acc.y;
            a_t[f4 + 2][ln] = acc.z;
            a_t[f4 + 3][ln] = acc.w;
        }
    }
    __syncthreads();
    int ty = t >> 4, tx = t & 15;
    int r0 = ty * 4, c0 = tx * 4;
    float am[4][4] = {};
#pragma unroll 4
    for (int k = 0; k < 64; ++k) {
        float4 av = *(const float4*)&a_t[k][r0];
        float4 wv = *(const float4*)(W + k * HID + c0);  // 16 KB, L1-resident, shared by all blocks
        am[0][0] += av.x * wv.x; am[0][1] += av.x * wv.y; am[0][2] += av.x * wv.z; am[0][3] += av.x * wv.w;
        am[1][0] += av.y * wv.x; am[1][1] += av.y * wv.y; am[1][2] += av.y * wv.z; am[1][3] += av.y * wv.w;
        am[2][0] += av.z * wv.x; am[2][1] += av.z * wv.y; am[2][2] += av.z * wv.z; am[2][3] += av.z * wv.w;
        am[3][0] += av.w * wv.x; am[3][1] += av.w * wv.y; am[3][2] += av.w * wv.z; am[3][3] += av.w * wv.w;
    }
    float4 bv = *(const float4*)(bias + c0);
#pragma unroll
    for (int i = 0; i < 4; ++i) {
        am[i][0] += bv.x; am[i][1] += bv.y; am[i][2] += bv.z; am[i][3] += bv.w;
    }
    if constexpr (EPI >= 1) {  // LayerNorm across 64 feats (feats live on the 16-thread tx group)
        float4 gv = *(const float4*)(g + c0);
        float4 bev = *(const float4*)(be + c0);
        float gg[4] = {gv.x, gv.y, gv.z, gv.w};
        float bb[4] = {bev.x, bev.y, bev.z, bev.w};
#pragma unroll
        for (int i = 0; i < 4; ++i) {
            float s = am[i][0] + am[i][1] + am[i][2] + am[i][3];
            float qv = am[i][0] * am[i][0] + am[i][1] * am[i][1] + am[i][2] * am[i][2] + am[i][3] * am[i][3];
#pragma unroll
            for (int m = 1; m < 16; m <<= 1) {
                s += __shfl_xor(s, m);
                qv += __shfl_xor(qv, m);
            }
            float mu = s * (1.0f / 64.0f);
            float var = qv * (1.0f / 64.0f) - mu * mu;
            float rstd = rsqrtf(var + EPSL);
#pragma unroll
            for (int j = 0; j < 4; ++j) am[i][j] = (am[i][j] - mu) * rstd * gg[j] + bb[j];
        }
    }
    const unsigned short* rb = resid + (size_t)b * (N_AREA * HID);
    if constexpr (EPI == 0) {
        unsigned short* ob = (unsigned short*)out + (size_t)b * (N_AREA * HID);
#pragma unroll
        for (int i = 0; i < 4; ++i) {
            int n = n0 + r0 + i;
            if (n < N_AREA) {
                uint2 rr = *(const uint2*)(rb + (size_t)n * HID + c0);
                float2 r01 = h2f2(rr.x), r23 = h2f2(rr.y);
                float o0 = lrelu(am[i][0]) + r01.x;
                float o1 = lrelu(am[i][1]) + r01.y;
                float o2 = lrelu(am[i][2]) + r23.x;
                float o3 = lrelu(am[i][3]) + r23.y;
                uint2 st;
                st.x = f2h2(o0, o1);
                st.y = f2h2(o2, o3);
                *(uint2*)(ob + (size_t)n * HID + c0) = st;
            }
        }
    } else {  // EPI == 2: finish h3 in-register, stash tile to LDS, GEMM2 with Wf, tanh, store fp32
        float* ob = (float*)out + (size_t)b * (N_AREA * HID);
#pragma unroll
        for (int i = 0; i < 4; ++i) {
            int n = n0 + r0 + i;
            int nc = n < N_AREA ? n : (N_AREA - 1);  // clamp OOB rows (values unused)
            uint2 rr = *(const uint2*)(rb + (size_t)nc * HID + c0);
            float2 r01 = h2f2(rr.x), r23 = h2f2(rr.y);
            am[i][0] = lrelu(am[i][0]) + r01.x;
            am[i][1] = lrelu(am[i][1]) + r01.y;
            am[i][2] = lrelu(am[i][2]) + r23.x;
            am[i][3] = lrelu(am[i][3]) + r23.y;
        }
        __syncthreads();  // all GEMM1 reads of a_t done
        float (*h3s)[68] = a_t;  // reuse as [node][feat]
#pragma unroll
        for (int i = 0; i < 4; ++i)
            *(float4*)&h3s[r0 + i][c0] = make_float4(am[i][0], am[i][1], am[i][2], am[i][3]);
        __syncthreads();
#pragma unroll
        for (int i = 0; i < 4; ++i) { am[i][0] = 0.f; am[i][1] = 0.f; am[i][2] = 0.f; am[i][3] = 0.f; }
#pragma unroll 4
        for (int k = 0; k < 64; ++k) {
            float4 wv = *(const float4*)(Wf + k * HID + c0);
            float a0 = h3s[r0 + 0][k];  // 4 distinct addrs per wave -> broadcast, conflict-free
            float a1 = h3s[r0 + 1][k];
            float a2 = h3s[r0 + 2][k];
            float a3 = h3s[r0 + 3][k];
            am[0][0] += a0 * wv.x; am[0][1] += a0 * wv.y; am[0][2] += a0 * wv.z; am[0][3] += a0 * wv.w;
            am[1][0] += a1 * wv.x; am[1][1] += a1 * wv.y; am[1][2] += a1 * wv.z; am[1][3] += a1 * wv.w;
            am[2][0] += a2 * wv.x; am[2][1] += a2 * wv.y; am[2][2] += a2 * wv.z; am[2][3] += a2 * wv.w;
            am[3][0] += a3 * wv.x; am[3][1] += a3 * wv.y; am[3][2] += a3 * wv.z; am[3][3] += a3 * wv.w;
        }
        float4 bfv = *(const float4*)(bf + c0);
#pragma unroll
        for (int i = 0; i < 4; ++i) {
            int n = n0 + r0 + i;
            if (n < N_AREA) {
                float4 o;
                o.x = tanh_fast(am[i][0] + bfv.x);
                o.y = tanh_fast(am[i][1] + bfv.y);
                o.z = tanh_fast(am[i][2] + bfv.z);
                o.w = tanh_fast(am[i][3] + bfv.w);
                *(float4*)(ob + (size_t)n * HID + c0) = o;
            }
        }
    }
}

extern "C" void kernel_launch(void* const* d_in, const int* in_sizes, int n_in,
                              void* d_out, int out_size, void* d_ws, size_t ws_size,
                              hipStream_t stream) {
    const float* state = (const float*)d_in[0];
    const int* ei = (const int*)d_in[1];
    const int E = in_sizes[1] / 2;
    const float* W1 = (const float*)d_in[5];
    const float* b1 = (const float*)d_in[6];
    const float* W2 = (const float*)d_in[7];
    const float* b2 = (const float*)d_in[8];
    const float* W3 = (const float*)d_in[9];
    const float* b3 = (const float*)d_in[10];
    const float* g1 = (const float*)d_in[11];
    const float* be1 = (const float*)d_in[12];
    const float* g3 = (const float*)d_in[13];
    const float* be3 = (const float*)d_in[14];
    const float* Wf = (const float*)d_in[15];
    const float* bf = (const float*)d_in[16];
    float* out = (float*)d_out;

    uint8_t* base = (uint8_t*)d_ws;
    size_t off = 0;
    auto carve = [&](size_t bytes) {
        void* p = base + off;
        off = (off + bytes + 255) & ~(size_t)255;
        return p;
    };
    float* dinv = (float*)carve(N_AREA * 4);
    int* counts = (int*)carve(N_AREA * 4);
    int* offsets = (int*)carve((N_AREA + 1) * 4);
    int* cursor = (int*)carve(N_AREA * 4);
    int2* ew = (int2*)carve(((size_t)E + 4 * N_AREA) * 8);  // padded edge list
    unsigned short* h1 = (unsigned short*)carve((size_t)BATCH * N_AREA * HID * 2);
    unsigned short* h2 = (unsigned short*)carve((size_t)BATCH * N_AREA * HID * 2);

    const int GRID = 8 * NCHUNK * (BATCH / 8);  // 10048

    k_zero<<<(N_AREA + 255) / 256, 256, 0, stream>>>(counts, N_AREA);
    k_hist<<<(E + 255) / 256, 256, 0, stream>>>(ei + E, counts, E);
    k_scan<<<1, 1024, 0, stream>>>(counts, offsets, cursor, dinv, ew);
    k_scatter<<<(E + 255) / 256, 256, 0, stream>>>(ei, dinv, cursor, ew, E);

    k_conv1<<<GRID, 256, 0, stream>>>(state, W1, b1, g1, be1, h1, offsets, ew);
    k_conv<0><<<GRID, 256, 0, stream>>>(h1, W2, b2, nullptr, nullptr, h1, h2, offsets, ew, nullptr, nullptr);
    k_conv<2><<<GRID, 256, 0, stream>>>(h2, W3, b3, g3, be3, h1, out, offsets, ew, Wf, bf);
}

// Round 6
// 1176.029 us; speedup vs baseline: 1.4985x; 1.2004x over previous
//
#include <hip/hip_runtime.h>
#include <hip/hip_fp16.h>
#include <cstdint>
#include <cstddef>

#define N_AREA 10000
#define N_FEAT 16
#define HID 64
#define BATCH 64
#define EPSL 1e-5f
#define SLOPE 0.01f
#define NCHUNK 157  // ceil(10000/64)

typedef float fv4 __attribute__((ext_vector_type(4)));

__device__ __forceinline__ float lrelu(float x) { return x >= 0.f ? x : SLOPE * x; }
__device__ __forceinline__ float tanh_fast(float x) {
    float t = __expf(2.0f * x);  // v_exp_f32 path
    return 1.0f - 2.0f / (t + 1.0f);
}
__device__ __forceinline__ float2 h2f2(unsigned u) {
    return __half22float2(*reinterpret_cast<const __half2*>(&u));
}
__device__ __forceinline__ unsigned f2h2(float a, float b) {
    __half2 h = __floats2half2_rn(a, b);
    return *reinterpret_cast<const unsigned*>(&h);
}
__device__ __forceinline__ fv4 cvt4(uint2 r) {
    float2 lo = h2f2(r.x), hi = h2f2(r.y);
    fv4 v = {lo.x, lo.y, hi.x, hi.y};
    return v;
}

__global__ __launch_bounds__(256) void k_zero(int* p, int n) {
    int i = blockIdx.x * 256 + threadIdx.x;
    if (i < n) p[i] = 0;
}

__global__ __launch_bounds__(256) void k_hist(const int* __restrict__ dst, int* __restrict__ counts, int E) {
    int e = blockIdx.x * 256 + threadIdx.x;
    if (e < E) atomicAdd(&counts[dst[e]], 1);
}

// offsets (exclusive, padded to x4 per node: 1 self-loop + real edges + weight-0 pads),
// dinv, self-loop entry, pad entries, cursor init. Tail: +64 zero edges so chunked
// wave-wide edge loads (ew[beg+lane]) never read past the allocation.
__global__ __launch_bounds__(1024) void k_scan(const int* __restrict__ counts, int* __restrict__ offsets,
                                               int* __restrict__ cursor, float* __restrict__ dinv,
                                               int2* __restrict__ ew) {
    const int PER = 10;
    int t = threadIdx.x;
    int base = t * PER;
    int local[PER];
    int sum = 0;
#pragma unroll
    for (int i = 0; i < PER; ++i) {
        int idx = base + i;
        int c = (idx < N_AREA) ? (((counts[idx] + 1) + 3) & ~3) : 0;  // padded count
        local[i] = sum;
        sum += c;
    }
    __shared__ int part[1024];
    part[t] = sum;
    __syncthreads();
    for (int off = 1; off < 1024; off <<= 1) {
        int v = (t >= off) ? part[t - off] : 0;
        __syncthreads();
        part[t] += v;
        __syncthreads();
    }
    int excl = (t == 0) ? 0 : part[t - 1];
    if (t == 1023) {
        int tot = part[1023];
        offsets[N_AREA] = tot;
        for (int i = 0; i < 64; ++i) ew[tot + i] = make_int2(0, 0);  // safe over-read tail
    }
    for (int i = 0; i < PER; ++i) {
        int idx = base + i;
        if (idx < N_AREA) {
            int off = excl + local[i];
            offsets[idx] = off;
            int c = counts[idx] + 1;          // real count (self + edges)
            int pc = (c + 3) & ~3;            // padded
            float dv = rsqrtf((float)c);
            dinv[idx] = dv;
            ew[off] = make_int2(idx, __float_as_int(dv * dv));  // self loop
            for (int pp = c; pp < pc; ++pp) ew[off + pp] = make_int2(idx, 0);  // weight-0 pads
            cursor[idx] = off + 1;
        }
    }
}

__global__ __launch_bounds__(256) void k_scatter(const int* __restrict__ ei, const float* __restrict__ dinv,
                                                 int* __restrict__ cursor, int2* __restrict__ ew, int E) {
    int e = blockIdx.x * 256 + threadIdx.x;
    if (e < E) {
        int s = ei[e], d = ei[E + e];
        int p = atomicAdd(&cursor[d], 1);
        ew[p] = make_int2(s, __float_as_int(dinv[s] * dinv[d]));
    }
}

// conv1 fused: gather(state rows of 16) -> @W1+b1 -> LN -> leaky -> h1 (fp16) [B][N][64]
__global__ __launch_bounds__(256, 8) void k_conv1(const float* __restrict__ state, const float* __restrict__ W1,
                                                  const float* __restrict__ b1, const float* __restrict__ g1,
                                                  const float* __restrict__ be1, unsigned short* __restrict__ h1,
                                                  const int* __restrict__ offs, const int2* __restrict__ ew) {
    __shared__ float xs[64][20];  // padded: node stride 20 floats keeps b128 aligned + banks spread
    __shared__ float ws[16][64];
    int blk = blockIdx.x;
    int xc = blk & 7, ii = blk >> 3;  // XCD group: batch b on XCD b%8
    int b = xc + 8 * (ii / NCHUNK);
    int c = ii % NCHUNK;
    int n0 = c * 64;
    int t = threadIdx.x;
    *(float4*)&ws[t >> 4][(t & 15) * 4] = *(const float4*)(W1 + (t >> 4) * HID + (t & 15) * 4);
    int ln = t >> 2, q = t & 3;
    int n = n0 + ln;
    const float* sb = state + (size_t)b * (N_AREA * N_FEAT);
    float4 acc = make_float4(0.f, 0.f, 0.f, 0.f);
    if (n < N_AREA) {
        int beg = offs[n], end = offs[n + 1];
        for (int e = beg; e < end; ++e) {
            int2 sw = ew[e];
            float w = __int_as_float(sw.y);
            float4 v = *(const float4*)(sb + (size_t)sw.x * N_FEAT + q * 4);
            acc.x += w * v.x; acc.y += w * v.y; acc.z += w * v.z; acc.w += w * v.w;
        }
    }
    *(float4*)&xs[ln][q * 4] = acc;
    __syncthreads();
    int wave = t >> 6, lane = t & 63;
    float bias = b1[lane], gg = g1[lane], bb = be1[lane];
    for (int j = 0; j < 16; ++j) {
        int lnn = wave * 16 + j;
        float a = bias;
#pragma unroll
        for (int f = 0; f < N_FEAT; ++f) a += xs[lnn][f] * ws[f][lane];
        float s = a;
#pragma unroll
        for (int m = 1; m < 64; m <<= 1) s += __shfl_xor(s, m);
        float mu = s * (1.0f / 64.0f);
        float dv = a - mu;
        float qv = dv * dv;
#pragma unroll
        for (int m = 1; m < 64; m <<= 1) qv += __shfl_xor(qv, m);
        float rstd = rsqrtf(qv * (1.0f / 64.0f) + EPSL);
        float y = lrelu(dv * rstd * gg + bb);
        int nn = n0 + lnn;
        // pack lane pairs -> one 4B store per even lane (h1 is fp16)
        unsigned hv = (unsigned)__half_as_ushort(__float2half_rn(y));
        unsigned ov = (unsigned)__shfl_xor((int)hv, 1);
        if (((lane & 1) == 0) && nn < N_AREA)
            *(unsigned*)(h1 + (size_t)b * (N_AREA * HID) + (size_t)nn * HID + lane) = hv | (ov << 16);
    }
}

// Fused conv over fp16 h: chunked edge gather. Per node, ONE wave-wide load grabs up to 64
// edge records (double-buffered across nodes); __shfl distributes them to the 16-lane quad
// groups, so all row loads issue dependency-free (deep MLP). 4 independent FMA chains.
// a_t uses the R4-verified granule-XOR swizzle (write conflicts 8-way -> 2-way).
// EPI 0: h2(fp16) = leaky(.+b) + resid(fp16 h1)
// EPI 2: h3 = leaky(LN(.+b)) + resid; out(fp32) = tanh(h3 @ Wf + bf)
template <int EPI>
__global__ __launch_bounds__(256, 8) void k_conv(const unsigned short* __restrict__ src, const float* __restrict__ W,
                                                 const float* __restrict__ bias, const float* __restrict__ g,
                                                 const float* __restrict__ be, const unsigned short* __restrict__ resid,
                                                 void* __restrict__ out, const int* __restrict__ offs,
                                                 const int2* __restrict__ ew, const float* __restrict__ Wf,
                                                 const float* __restrict__ bf) {
    __shared__ float a_t[64][68];  // [feat][node], swizzled granules; reused [node][feat] for fused GEMM2
    int blk = blockIdx.x;
    int xc = blk & 7, ii = blk >> 3;
    int b = xc + 8 * (ii / NCHUNK);
    int c = ii % NCHUNK;
    int n0 = c * 64;
    int t = threadIdx.x;
    int lane = t & 63;
    int wave = __builtin_amdgcn_readfirstlane(t) >> 6;  // provably wave-uniform -> scalar offs
    int q = lane >> 4;         // quad group: which edge of a quad this lane handles
    int ql = lane & 15;
    int f4 = ql * 4;           // feature base (4 halves = 8B per lane)
    const unsigned short* sp = src + (size_t)b * (N_AREA * HID);
    int nb = n0 + wave * 16;   // first node of this wave (uniform)
    int beg = 0, end = 0;
    if (nb < N_AREA) { beg = offs[nb]; end = offs[nb + 1]; }
    int2 eC = ew[beg + lane];  // edge chunk for node 0 (one wave-wide dwordx2)
    for (int j = 0; j < 16; ++j) {
        int n = nb + j;  // uniform
        int cnt = (n < N_AREA) ? (end - beg) : 0;
        // prefetch next node's chunk while we consume this one
        int nbeg = end;
        int nend = (n + 1 < N_AREA) ? offs[n + 2] : end;
        int2 eN = ew[nbeg + lane];
        int cmin = cnt > 64 ? 64 : cnt;
        fv4 a0 = {0.f, 0.f, 0.f, 0.f}, a1 = a0, a2 = a0, a3 = a0;
        int k16 = cmin >> 4;  // 16-edge super-iters, 4 independent chains
        for (int k = 0; k < k16; ++k) {
            int s0 = 16 * k + q;
            int xa = __shfl(eC.x, s0),      wa = __shfl(eC.y, s0);
            int xb = __shfl(eC.x, s0 + 4),  wb = __shfl(eC.y, s0 + 4);
            int xc2 = __shfl(eC.x, s0 + 8), wc = __shfl(eC.y, s0 + 8);
            int xd = __shfl(eC.x, s0 + 12), wd = __shfl(eC.y, s0 + 12);
            uint2 ra = *(const uint2*)(sp + (unsigned)xa * HID + f4);
            uint2 rb = *(const uint2*)(sp + (unsigned)xb * HID + f4);
            uint2 rc = *(const uint2*)(sp + (unsigned)xc2 * HID + f4);
            uint2 rd = *(const uint2*)(sp + (unsigned)xd * HID + f4);
            a0 += __int_as_float(wa) * cvt4(ra);
            a1 += __int_as_float(wb) * cvt4(rb);
            a2 += __int_as_float(wc) * cvt4(rc);
            a3 += __int_as_float(wd) * cvt4(rd);
        }
        for (int e4 = k16 * 16; e4 < cmin; e4 += 4) {  // remaining quads (padded x4: 0..3 of them)
            int sl = e4 + q;
            int xa = __shfl(eC.x, sl), wa = __shfl(eC.y, sl);
            uint2 ra = *(const uint2*)(sp + (unsigned)xa * HID + f4);
            a0 += __int_as_float(wa) * cvt4(ra);
        }
        if (cnt > 64) {  // rare fallback: direct quad loads for the overflow
            for (int e = beg + 64; e < end; e += 4) {
                int2 ea = ew[e + q];
                uint2 ra = *(const uint2*)(sp + (unsigned)ea.x * HID + f4);
                a0 += __int_as_float(ea.y) * cvt4(ra);
            }
        }
        // merge chains, reduce across quads (lanes L, L^16, L^32, L^48 share features)
        fv4 acc = (a0 + a1) + (a2 + a3);
        acc.x += __shfl_xor(acc.x, 16); acc.y += __shfl_xor(acc.y, 16);
        acc.z += __shfl_xor(acc.z, 16); acc.w += __shfl_xor(acc.w, 16);
        acc.x += __shfl_xor(acc.x, 32); acc.y += __shfl_xor(acc.y, 32);
        acc.z += __shfl_xor(acc.z, 32); acc.w += __shfl_xor(acc.w, 32);
        if (q == 0) {
            int ln = wave * 16 + j;
            int colp = 4 * ((ln >> 2) ^ (ql & 7)) + (ln & 3);  // granule-XOR swizzle (R4-verified)
            a_t[f4 + 0][colp] = acc.x;
            a_t[f4 + 1][colp] = acc.y;
            a_t[f4 + 2][colp] = acc.z;
            a_t[f4 + 3][colp] = acc.w;
        }
        eC = eN; beg = nbeg; end = nend;
    }
    __syncthreads();
    int ty = t >> 4, tx = t & 15;
    int r0 = ty * 4, c0 = tx * 4;
    float am[4][4] = {};
#pragma unroll 4
    for (int k = 0; k < 64; ++k) {
        fv4 av = *(const fv4*)&a_t[k][4 * (ty ^ ((k >> 2) & 7))];  // inverse swizzle -> nodes r0..r0+3
        float4 wv = *(const float4*)(W + k * HID + c0);  // 16 KB, L1-resident, shared by all blocks
        am[0][0] += av.x * wv.x; am[0][1] += av.x * wv.y; am[0][2] += av.x * wv.z; am[0][3] += av.x * wv.w;
        am[1][0] += av.y * wv.x; am[1][1] += av.y * wv.y; am[1][2] += av.y * wv.z; am[1][3] += av.y * wv.w;
        am[2][0] += av.z * wv.x; am[2][1] += av.z * wv.y; am[2][2] += av.z * wv.z; am[2][3] += av.z * wv.w;
        am[3][0] += av.w * wv.x; am[3][1] += av.w * wv.y; am[3][2] += av.w * wv.z; am[3][3] += av.w * wv.w;
    }
    float4 bv = *(const float4*)(bias + c0);
#pragma unroll
    for (int i = 0; i < 4; ++i) {
        am[i][0] += bv.x; am[i][1] += bv.y; am[i][2] += bv.z; am[i][3] += bv.w;
    }
    if constexpr (EPI >= 1) {  // LayerNorm across 64 feats (feats live on the 16-thread tx group)
        float4 gv = *(const float4*)(g + c0);
        float4 bev = *(const float4*)(be + c0);
        float gg[4] = {gv.x, gv.y, gv.z, gv.w};
        float bb[4] = {bev.x, bev.y, bev.z, bev.w};
#pragma unroll
        for (int i = 0; i < 4; ++i) {
            float s = am[i][0] + am[i][1] + am[i][2] + am[i][3];
            float qv = am[i][0] * am[i][0] + am[i][1] * am[i][1] + am[i][2] * am[i][2] + am[i][3] * am[i][3];
#pragma unroll
            for (int m = 1; m < 16; m <<= 1) {
                s += __shfl_xor(s, m);
                qv += __shfl_xor(qv, m);
            }
            float mu = s * (1.0f / 64.0f);
            float var = qv * (1.0f / 64.0f) - mu * mu;
            float rstd = rsqrtf(var + EPSL);
#pragma unroll
            for (int j = 0; j < 4; ++j) am[i][j] = (am[i][j] - mu) * rstd * gg[j] + bb[j];
        }
    }
    const unsigned short* rb = resid + (size_t)b * (N_AREA * HID);
    if constexpr (EPI == 0) {
        unsigned short* ob = (unsigned short*)out + (size_t)b * (N_AREA * HID);
#pragma unroll
        for (int i = 0; i < 4; ++i) {
            int n = n0 + r0 + i;
            if (n < N_AREA) {
                uint2 rr = *(const uint2*)(rb + (size_t)n * HID + c0);
                float2 r01 = h2f2(rr.x), r23 = h2f2(rr.y);
                float o0 = lrelu(am[i][0]) + r01.x;
                float o1 = lrelu(am[i][1]) + r01.y;
                float o2 = lrelu(am[i][2]) + r23.x;
                float o3 = lrelu(am[i][3]) + r23.y;
                uint2 st;
                st.x = f2h2(o0, o1);
                st.y = f2h2(o2, o3);
                *(uint2*)(ob + (size_t)n * HID + c0) = st;
            }
        }
    } else {  // EPI == 2: finish h3 in-register, stash tile to LDS, GEMM2 with Wf, tanh, store fp32
        float* ob = (float*)out + (size_t)b * (N_AREA * HID);
#pragma unroll
        for (int i = 0; i < 4; ++i) {
            int n = n0 + r0 + i;
            int nc = n < N_AREA ? n : (N_AREA - 1);  // clamp OOB rows (values unused)
            uint2 rr = *(const uint2*)(rb + (size_t)nc * HID + c0);
            float2 r01 = h2f2(rr.x), r23 = h2f2(rr.y);
            am[i][0] = lrelu(am[i][0]) + r01.x;
            am[i][1] = lrelu(am[i][1]) + r01.y;
            am[i][2] = lrelu(am[i][2]) + r23.x;
            am[i][3] = lrelu(am[i][3]) + r23.y;
        }
        __syncthreads();  // all GEMM1 reads of a_t done
        float (*h3s)[68] = a_t;  // reuse as [node][feat], plain layout
#pragma unroll
        for (int i = 0; i < 4; ++i)
            *(float4*)&h3s[r0 + i][c0] = make_float4(am[i][0], am[i][1], am[i][2], am[i][3]);
        __syncthreads();
#pragma unroll
        for (int i = 0; i < 4; ++i) { am[i][0] = 0.f; am[i][1] = 0.f; am[i][2] = 0.f; am[i][3] = 0.f; }
#pragma unroll 4
        for (int k = 0; k < 64; ++k) {
            float4 wv = *(const float4*)(Wf + k * HID + c0);
            float a0 = h3s[r0 + 0][k];  // 4 distinct addrs per wave -> broadcast, conflict-free
            float a1 = h3s[r0 + 1][k];
            float a2 = h3s[r0 + 2][k];
            float a3 = h3s[r0 + 3][k];
            am[0][0] += a0 * wv.x; am[0][1] += a0 * wv.y; am[0][2] += a0 * wv.z; am[0][3] += a0 * wv.w;
            am[1][0] += a1 * wv.x; am[1][1] += a1 * wv.y; am[1][2] += a1 * wv.z; am[1][3] += a1 * wv.w;
            am[2][0] += a2 * wv.x; am[2][1] += a2 * wv.y; am[2][2] += a2 * wv.z; am[2][3] += a2 * wv.w;
            am[3][0] += a3 * wv.x; am[3][1] += a3 * wv.y; am[3][2] += a3 * wv.z; am[3][3] += a3 * wv.w;
        }
        float4 bfv = *(const float4*)(bf + c0);
#pragma unroll
        for (int i = 0; i < 4; ++i) {
            int n = n0 + r0 + i;
            if (n < N_AREA) {
                float4 o;
                o.x = tanh_fast(am[i][0] + bfv.x);
                o.y = tanh_fast(am[i][1] + bfv.y);
                o.z = tanh_fast(am[i][2] + bfv.z);
                o.w = tanh_fast(am[i][3] + bfv.w);
                *(float4*)(ob + (size_t)n * HID + c0) = o;
            }
        }
    }
}

extern "C" void kernel_launch(void* const* d_in, const int* in_sizes, int n_in,
                              void* d_out, int out_size, void* d_ws, size_t ws_size,
                              hipStream_t stream) {
    const float* state = (const float*)d_in[0];
    const int* ei = (const int*)d_in[1];
    const int E = in_sizes[1] / 2;
    const float* W1 = (const float*)d_in[5];
    const float* b1 = (const float*)d_in[6];
    const float* W2 = (const float*)d_in[7];
    const float* b2 = (const float*)d_in[8];
    const float* W3 = (const float*)d_in[9];
    const float* b3 = (const float*)d_in[10];
    const float* g1 = (const float*)d_in[11];
    const float* be1 = (const float*)d_in[12];
    const float* g3 = (const float*)d_in[13];
    const float* be3 = (const float*)d_in[14];
    const float* Wf = (const float*)d_in[15];
    const float* bf = (const float*)d_in[16];
    float* out = (float*)d_out;

    uint8_t* base = (uint8_t*)d_ws;
    size_t off = 0;
    auto carve = [&](size_t bytes) {
        void* p = base + off;
        off = (off + bytes + 255) & ~(size_t)255;
        return p;
    };
    float* dinv = (float*)carve(N_AREA * 4);
    int* counts = (int*)carve(N_AREA * 4);
    int* offsets = (int*)carve((N_AREA + 1) * 4);
    int* cursor = (int*)carve(N_AREA * 4);
    int2* ew = (int2*)carve(((size_t)E + 4 * N_AREA + 64) * 8);  // padded edge list + over-read tail
    unsigned short* h1 = (unsigned short*)carve((size_t)BATCH * N_AREA * HID * 2);
    unsigned short* h2 = (unsigned short*)carve((size_t)BATCH * N_AREA * HID * 2);

    const int GRID = 8 * NCHUNK * (BATCH / 8);  // 10048

    k_zero<<<(N_AREA + 255) / 256, 256, 0, stream>>>(counts, N_AREA);
    k_hist<<<(E + 255) / 256, 256, 0, stream>>>(ei + E, counts, E);
    k_scan<<<1, 1024, 0, stream>>>(counts, offsets, cursor, dinv, ew);
    k_scatter<<<(E + 255) / 256, 256, 0, stream>>>(ei, dinv, cursor, ew, E);

    k_conv1<<<GRID, 256, 0, stream>>>(state, W1, b1, g1, be1, h1, offsets, ew);
    k_conv<0><<<GRID, 256, 0, stream>>>(h1, W2, b2, nullptr, nullptr, h1, h2, offsets, ew, nullptr, nullptr);
    k_conv<2><<<GRID, 256, 0, stream>>>(h2, W3, b3, g3, be3, h1, out, offsets, ew, Wf, bf);
}

// Round 11
// 1058.928 us; speedup vs baseline: 1.6642x; 1.1106x over previous
//
#include <hip/hip_runtime.h>
#include <hip/hip_fp16.h>
#include <cstdint>
#include <cstddef>

#define N_AREA 10000
#define N_FEAT 16
#define HID 64
#define BATCH 64
#define EPSL 1e-5f
#define SLOPE 0.01f
#define NCHUNK 157  // ceil(10000/64)

typedef float fv4 __attribute__((ext_vector_type(4)));
typedef _Float16 h4 __attribute__((ext_vector_type(4)));

__device__ __forceinline__ float lrelu(float x) { return x >= 0.f ? x : SLOPE * x; }
__device__ __forceinline__ float tanh_fast(float x) {
    float t = __expf(2.0f * x);  // v_exp_f32 path
    return 1.0f - 2.0f / (t + 1.0f);
}
__device__ __forceinline__ float2 h2f2(unsigned u) {
    return __half22float2(*reinterpret_cast<const __half2*>(&u));
}
__device__ __forceinline__ unsigned f2h2(float a, float b) {
    __half2 h = __floats2half2_rn(a, b);
    return *reinterpret_cast<const unsigned*>(&h);
}
__device__ __forceinline__ fv4 cvt4(uint2 r) {
    float2 lo = h2f2(r.x), hi = h2f2(r.y);
    fv4 v = {lo.x, lo.y, hi.x, hi.y};
    return v;
}
__device__ __forceinline__ h4 pack4(float a, float b, float c, float d) {
    auto p0 = __builtin_amdgcn_cvt_pkrtz(a, b);  // __fp16x2 (layout == _Float16x2)
    auto p1 = __builtin_amdgcn_cvt_pkrtz(c, d);
    h4 r;
    *reinterpret_cast<decltype(p0)*>(&r) = p0;
    *(reinterpret_cast<decltype(p0)*>(&r) + 1) = p1;
    return r;
}

__global__ __launch_bounds__(256) void k_zero(int* p, int n) {
    int i = blockIdx.x * 256 + threadIdx.x;
    if (i < n) p[i] = 0;
}

__global__ __launch_bounds__(256) void k_hist(const int* __restrict__ dst, int* __restrict__ counts, int E) {
    int e = blockIdx.x * 256 + threadIdx.x;
    if (e < E) atomicAdd(&counts[dst[e]], 1);
}

// Pre-pack W2/W3/Wf into fp16 MFMA A-fragment order (A = W^T):
// frag[((mt*4+kk)*64 + lane)*4 + i] = W[16kk + 4(lane>>4) + i][16mt + (lane&15)]
__global__ __launch_bounds__(256) void k_wcvt(const float* __restrict__ Wa, const float* __restrict__ Wb,
                                              const float* __restrict__ Wc, _Float16* __restrict__ fa,
                                              _Float16* __restrict__ fb, _Float16* __restrict__ fc) {
    int t = threadIdx.x;
    int lane = t & 63, pg = t >> 6;
    int g = lane >> 4, q = lane & 15;
    for (int p = pg; p < 16; p += 4) {
        int mt = p >> 2, kk = p & 3;
        int sb = (16 * kk + 4 * g) * HID + 16 * mt + q;
        int dst = (p * 64 + lane) * 4;
        for (int i = 0; i < 4; ++i) {
            fa[dst + i] = (_Float16)Wa[sb + i * HID];
            fb[dst + i] = (_Float16)Wb[sb + i * HID];
            fc[dst + i] = (_Float16)Wc[sb + i * HID];
        }
    }
}

// offsets (exclusive, padded to x4 per node: 1 self-loop + real edges + weight-0 pads),
// dinv, self-loop entry, pad entries, cursor init. Tail: +64 zero edges for chunked loads.
__global__ __launch_bounds__(1024) void k_scan(const int* __restrict__ counts, int* __restrict__ offsets,
                                               int* __restrict__ cursor, float* __restrict__ dinv,
                                               int2* __restrict__ ew) {
    const int PER = 10;
    int t = threadIdx.x;
    int base = t * PER;
    int local[PER];
    int sum = 0;
#pragma unroll
    for (int i = 0; i < PER; ++i) {
        int idx = base + i;
        int c = (idx < N_AREA) ? (((counts[idx] + 1) + 3) & ~3) : 0;  // padded count
        local[i] = sum;
        sum += c;
    }
    __shared__ int part[1024];
    part[t] = sum;
    __syncthreads();
    for (int off = 1; off < 1024; off <<= 1) {
        int v = (t >= off) ? part[t - off] : 0;
        __syncthreads();
        part[t] += v;
        __syncthreads();
    }
    int excl = (t == 0) ? 0 : part[t - 1];
    if (t == 1023) {
        int tot = part[1023];
        offsets[N_AREA] = tot;
        for (int i = 0; i < 64; ++i) ew[tot + i] = make_int2(0, 0);  // safe over-read tail
    }
    for (int i = 0; i < PER; ++i) {
        int idx = base + i;
        if (idx < N_AREA) {
            int off = excl + local[i];
            offsets[idx] = off;
            int c = counts[idx] + 1;          // real count (self + edges)
            int pc = (c + 3) & ~3;            // padded
            float dv = rsqrtf((float)c);
            dinv[idx] = dv;
            ew[off] = make_int2(idx, __float_as_int(dv * dv));  // self loop
            for (int pp = c; pp < pc; ++pp) ew[off + pp] = make_int2(idx, 0);  // weight-0 pads
            cursor[idx] = off + 1;
        }
    }
}

__global__ __launch_bounds__(256) void k_scatter(const int* __restrict__ ei, const float* __restrict__ dinv,
                                                 int* __restrict__ cursor, int2* __restrict__ ew, int E) {
    int e = blockIdx.x * 256 + threadIdx.x;
    if (e < E) {
        int s = ei[e], d = ei[E + e];
        int p = atomicAdd(&cursor[d], 1);
        ew[p] = make_int2(s, __float_as_int(dinv[s] * dinv[d]));
    }
}

// conv1 fused: gather(state rows of 16) -> @W1+b1 -> LN -> leaky -> h1 (fp16) [B][N][64]
__global__ __launch_bounds__(256, 8) void k_conv1(const float* __restrict__ state, const float* __restrict__ W1,
                                                  const float* __restrict__ b1, const float* __restrict__ g1,
                                                  const float* __restrict__ be1, unsigned short* __restrict__ h1,
                                                  const int* __restrict__ offs, const int2* __restrict__ ew) {
    __shared__ float xs[64][20];
    __shared__ float ws[16][64];
    int blk = blockIdx.x;
    int xc = blk & 7, ii = blk >> 3;  // XCD group: batch b on XCD b%8
    int b = xc + 8 * (ii / NCHUNK);
    int c = ii % NCHUNK;
    int n0 = c * 64;
    int t = threadIdx.x;
    *(float4*)&ws[t >> 4][(t & 15) * 4] = *(const float4*)(W1 + (t >> 4) * HID + (t & 15) * 4);
    int ln = t >> 2, q = t & 3;
    int n = n0 + ln;
    const float* sb = state + (size_t)b * (N_AREA * N_FEAT);
    float4 acc = make_float4(0.f, 0.f, 0.f, 0.f);
    if (n < N_AREA) {
        int beg = offs[n], end = offs[n + 1];
        for (int e = beg; e < end; ++e) {
            int2 sw = ew[e];
            float w = __int_as_float(sw.y);
            float4 v = *(const float4*)(sb + (size_t)sw.x * N_FEAT + q * 4);
            acc.x += w * v.x; acc.y += w * v.y; acc.z += w * v.z; acc.w += w * v.w;
        }
    }
    *(float4*)&xs[ln][q * 4] = acc;
    __syncthreads();
    int wave = t >> 6, lane = t & 63;
    float bias = b1[lane], gg = g1[lane], bb = be1[lane];
    for (int j = 0; j < 16; ++j) {
        int lnn = wave * 16 + j;
        float a = bias;
#pragma unroll
        for (int f = 0; f < N_FEAT; ++f) a += xs[lnn][f] * ws[f][lane];
        float s = a;
#pragma unroll
        for (int m = 1; m < 64; m <<= 1) s += __shfl_xor(s, m);
        float mu = s * (1.0f / 64.0f);
        float dv = a - mu;
        float qv = dv * dv;
#pragma unroll
        for (int m = 1; m < 64; m <<= 1) qv += __shfl_xor(qv, m);
        float rstd = rsqrtf(qv * (1.0f / 64.0f) + EPSL);
        float y = lrelu(dv * rstd * gg + bb);
        int nn = n0 + lnn;
        unsigned hv = (unsigned)__half_as_ushort(__float2half_rn(y));
        unsigned ov = (unsigned)__shfl_xor((int)hv, 1);
        if (((lane & 1) == 0) && nn < N_AREA)
            *(unsigned*)(h1 + (size_t)b * (N_AREA * HID) + (size_t)nn * HID + lane) = hv | (ov << 16);
    }
}

// Fused conv: chunked edge gather (R6) -> MFMA GEMM1 (out^T = W^T x a^T) -> epilogue.
// a_t layout [feat][node] with granule-XOR swizzle phys(f,c) = 4*((c>>2)^((f>>2)&7)) + (c&3).
// MFMA 16x16x16_f16: A[m=l&15][k=4(l>>4)+i], B[k=4(l>>4)+i][n=l&15], D[m=4(l>>4)+i][n=l&15].
// Lane holds: node nd = n0+16*wave+(l&15); feats 16mt+4(l>>4)+i  -> consecutive-feat stores.
// EPI 0: h2(fp16) = leaky(.+b) + resid
// EPI 2: h3 = leaky(LN(.+b)) + resid; h3 D-frags ARE GEMM2 B-frags (in-register); out = tanh(h3@Wf+bf)
template <int EPI>
__global__ __launch_bounds__(256, 8) void k_conv(const unsigned short* __restrict__ src,
                                                 const _Float16* __restrict__ Wfrag,
                                                 const float* __restrict__ bias, const float* __restrict__ g,
                                                 const float* __restrict__ be, const unsigned short* __restrict__ resid,
                                                 void* __restrict__ out, const int* __restrict__ offs,
                                                 const int2* __restrict__ ew, const _Float16* __restrict__ WfFrag,
                                                 const float* __restrict__ bf) {
    __shared__ float a_t[64][68];
    int blk = blockIdx.x;
    int xc = blk & 7, ii = blk >> 3;
    int b = xc + 8 * (ii / NCHUNK);
    int c = ii % NCHUNK;
    int n0 = c * 64;
    int t = threadIdx.x;
    int lane = t & 63;
    int wave = __builtin_amdgcn_readfirstlane(t) >> 6;  // provably wave-uniform -> scalar offs
    int q = lane >> 4;         // quad group (gather) == k-group g (MFMA)
    int ql = lane & 15;
    int f4 = ql * 4;
    const unsigned short* sp = src + (size_t)b * (N_AREA * HID);
    int nb = n0 + wave * 16;
    int beg = 0, end = 0;
    if (nb < N_AREA) { beg = offs[nb]; end = offs[nb + 1]; }
    int2 eC = ew[beg + lane];
    for (int j = 0; j < 16; ++j) {
        int n = nb + j;
        int cnt = (n < N_AREA) ? (end - beg) : 0;
        int nbeg = end;
        int nend = (n + 1 < N_AREA) ? offs[n + 2] : end;
        int2 eN = ew[nbeg + lane];
        int cmin = cnt > 64 ? 64 : cnt;
        fv4 a0 = {0.f, 0.f, 0.f, 0.f}, a1 = a0, a2 = a0, a3 = a0;
        int k16 = cmin >> 4;
        for (int k = 0; k < k16; ++k) {
            int s0 = 16 * k + q;
            int xa = __shfl(eC.x, s0),      wa = __shfl(eC.y, s0);
            int xb = __shfl(eC.x, s0 + 4),  wb = __shfl(eC.y, s0 + 4);
            int xc2 = __shfl(eC.x, s0 + 8), wc = __shfl(eC.y, s0 + 8);
            int xd = __shfl(eC.x, s0 + 12), wd = __shfl(eC.y, s0 + 12);
            uint2 ra = *(const uint2*)(sp + (unsigned)xa * HID + f4);
            uint2 rb = *(const uint2*)(sp + (unsigned)xb * HID + f4);
            uint2 rc = *(const uint2*)(sp + (unsigned)xc2 * HID + f4);
            uint2 rd = *(const uint2*)(sp + (unsigned)xd * HID + f4);
            a0 += __int_as_float(wa) * cvt4(ra);
            a1 += __int_as_float(wb) * cvt4(rb);
            a2 += __int_as_float(wc) * cvt4(rc);
            a3 += __int_as_float(wd) * cvt4(rd);
        }
        for (int e4 = k16 * 16; e4 < cmin; e4 += 4) {
            int sl = e4 + q;
            int xa = __shfl(eC.x, sl), wa = __shfl(eC.y, sl);
            uint2 ra = *(const uint2*)(sp + (unsigned)xa * HID + f4);
            a0 += __int_as_float(wa) * cvt4(ra);
        }
        if (cnt > 64) {
            for (int e = beg + 64; e < end; e += 4) {
                int2 ea = ew[e + q];
                uint2 ra = *(const uint2*)(sp + (unsigned)ea.x * HID + f4);
                a0 += __int_as_float(ea.y) * cvt4(ra);
            }
        }
        fv4 acc = (a0 + a1) + (a2 + a3);
        acc.x += __shfl_xor(acc.x, 16); acc.y += __shfl_xor(acc.y, 16);
        acc.z += __shfl_xor(acc.z, 16); acc.w += __shfl_xor(acc.w, 16);
        acc.x += __shfl_xor(acc.x, 32); acc.y += __shfl_xor(acc.y, 32);
        acc.z += __shfl_xor(acc.z, 32); acc.w += __shfl_xor(acc.w, 32);
        if (q == 0) {
            int ln = wave * 16 + j;
            int colp = 4 * ((ln >> 2) ^ (ql & 7)) + (ln & 3);  // granule-XOR swizzle
            a_t[f4 + 0][colp] = acc.x;
            a_t[f4 + 1][colp] = acc.y;
            a_t[f4 + 2][colp] = acc.z;
            a_t[f4 + 3][colp] = acc.w;
        }
        eC = eN; beg = nbeg; end = nend;
    }
    __syncthreads();
    // ---- MFMA GEMM1: acc[mt] = out^T tile, lane: node nd, feats 16mt+4q+i ----
    fv4 acc[4] = {{0.f, 0.f, 0.f, 0.f}, {0.f, 0.f, 0.f, 0.f}, {0.f, 0.f, 0.f, 0.f}, {0.f, 0.f, 0.f, 0.f}};
#pragma unroll
    for (int kk = 0; kk < 4; ++kk) {
        int f0 = 16 * kk + 4 * q;
        int colp = 4 * ((4 * wave + (ql >> 2)) ^ ((4 * kk + q) & 7)) + (ql & 3);  // inverse swizzle
        float b0 = a_t[f0 + 0][colp];
        float b1 = a_t[f0 + 1][colp];
        float b2 = a_t[f0 + 2][colp];
        float b3 = a_t[f0 + 3][colp];
        h4 bfr = pack4(b0, b1, b2, b3);
#pragma unroll
        for (int mt = 0; mt < 4; ++mt) {
            h4 af = *(const h4*)(Wfrag + ((mt * 4 + kk) * 64 + lane) * 4);
            acc[mt] = __builtin_amdgcn_mfma_f32_16x16x16f16(af, bfr, acc[mt], 0, 0, 0);
        }
    }
    int nd = n0 + 16 * wave + ql;
#pragma unroll
    for (int mt = 0; mt < 4; ++mt) {
        float4 bv = *(const float4*)(bias + 16 * mt + 4 * q);
        acc[mt].x += bv.x; acc[mt].y += bv.y; acc[mt].z += bv.z; acc[mt].w += bv.w;
    }
    if constexpr (EPI >= 1) {  // LayerNorm over 64 feats: per-lane 16 vals + reduce across k-groups
        float s = 0.f, qv = 0.f;
#pragma unroll
        for (int mt = 0; mt < 4; ++mt) {
            s += acc[mt].x + acc[mt].y + acc[mt].z + acc[mt].w;
            qv += acc[mt].x * acc[mt].x + acc[mt].y * acc[mt].y + acc[mt].z * acc[mt].z + acc[mt].w * acc[mt].w;
        }
        s += __shfl_xor(s, 16); s += __shfl_xor(s, 32);
        qv += __shfl_xor(qv, 16); qv += __shfl_xor(qv, 32);
        float mu = s * (1.0f / 64.0f);
        float var = qv * (1.0f / 64.0f) - mu * mu;
        float rstd = rsqrtf(var + EPSL);
#pragma unroll
        for (int mt = 0; mt < 4; ++mt) {
            float4 gv = *(const float4*)(g + 16 * mt + 4 * q);
            float4 bev = *(const float4*)(be + 16 * mt + 4 * q);
            acc[mt].x = (acc[mt].x - mu) * rstd * gv.x + bev.x;
            acc[mt].y = (acc[mt].y - mu) * rstd * gv.y + bev.y;
            acc[mt].z = (acc[mt].z - mu) * rstd * gv.z + bev.z;
            acc[mt].w = (acc[mt].w - mu) * rstd * gv.w + bev.w;
        }
    }
    const unsigned short* rb = resid + (size_t)b * (N_AREA * HID);
    if constexpr (EPI == 0) {
        unsigned short* ob = (unsigned short*)out + (size_t)b * (N_AREA * HID);
        if (nd < N_AREA) {
            size_t rowo = (size_t)nd * HID;
#pragma unroll
            for (int mt = 0; mt < 4; ++mt) {
                int fo = 16 * mt + 4 * q;
                uint2 rr = *(const uint2*)(rb + rowo + fo);
                float2 r01 = h2f2(rr.x), r23 = h2f2(rr.y);
                float o0 = lrelu(acc[mt].x) + r01.x;
                float o1 = lrelu(acc[mt].y) + r01.y;
                float o2 = lrelu(acc[mt].z) + r23.x;
                float o3 = lrelu(acc[mt].w) + r23.y;
                uint2 st;
                st.x = f2h2(o0, o1);
                st.y = f2h2(o2, o3);
                *(uint2*)(ob + rowo + fo) = st;
            }
        }
    } else {  // EPI == 2: finish h3 in-register; D-frags double as GEMM2 B-frags
        int ncl = nd < N_AREA ? nd : (N_AREA - 1);
        size_t rowo = (size_t)ncl * HID;
        h4 h3f[4];
#pragma unroll
        for (int mt = 0; mt < 4; ++mt) {
            int fo = 16 * mt + 4 * q;
            uint2 rr = *(const uint2*)(rb + rowo + fo);
            float2 r01 = h2f2(rr.x), r23 = h2f2(rr.y);
            float v0 = lrelu(acc[mt].x) + r01.x;
            float v1 = lrelu(acc[mt].y) + r01.y;
            float v2 = lrelu(acc[mt].z) + r23.x;
            float v3 = lrelu(acc[mt].w) + r23.y;
            h3f[mt] = pack4(v0, v1, v2, v3);
        }
        fv4 acc2[4] = {{0.f, 0.f, 0.f, 0.f}, {0.f, 0.f, 0.f, 0.f}, {0.f, 0.f, 0.f, 0.f}, {0.f, 0.f, 0.f, 0.f}};
#pragma unroll
        for (int kk = 0; kk < 4; ++kk) {
#pragma unroll
            for (int mt = 0; mt < 4; ++mt) {
                h4 af = *(const h4*)(WfFrag + ((mt * 4 + kk) * 64 + lane) * 4);
                acc2[mt] = __builtin_amdgcn_mfma_f32_16x16x16f16(af, h3f[kk], acc2[mt], 0, 0, 0);
            }
        }
        float* ob = (float*)out + (size_t)b * (N_AREA * HID);
        if (nd < N_AREA) {
#pragma unroll
            for (int mt = 0; mt < 4; ++mt) {
                float4 bfv = *(const float4*)(bf + 16 * mt + 4 * q);
                float4 o;
                o.x = tanh_fast(acc2[mt].x + bfv.x);
                o.y = tanh_fast(acc2[mt].y + bfv.y);
                o.z = tanh_fast(acc2[mt].z + bfv.z);
                o.w = tanh_fast(acc2[mt].w + bfv.w);
                *(float4*)(ob + (size_t)nd * HID + 16 * mt + 4 * q) = o;
            }
        }
    }
}

extern "C" void kernel_launch(void* const* d_in, const int* in_sizes, int n_in,
                              void* d_out, int out_size, void* d_ws, size_t ws_size,
                              hipStream_t stream) {
    const float* state = (const float*)d_in[0];
    const int* ei = (const int*)d_in[1];
    const int E = in_sizes[1] / 2;
    const float* W1 = (const float*)d_in[5];
    const float* b1 = (const float*)d_in[6];
    const float* W2 = (const float*)d_in[7];
    const float* b2 = (const float*)d_in[8];
    const float* W3 = (const float*)d_in[9];
    const float* b3 = (const float*)d_in[10];
    const float* g1 = (const float*)d_in[11];
    const float* be1 = (const float*)d_in[12];
    const float* g3 = (const float*)d_in[13];
    const float* be3 = (const float*)d_in[14];
    const float* Wf = (const float*)d_in[15];
    const float* bf = (const float*)d_in[16];
    float* out = (float*)d_out;

    uint8_t* base = (uint8_t*)d_ws;
    size_t off = 0;
    auto carve = [&](size_t bytes) {
        void* p = base + off;
        off = (off + bytes + 255) & ~(size_t)255;
        return p;
    };
    float* dinv = (float*)carve(N_AREA * 4);
    int* counts = (int*)carve(N_AREA * 4);
    int* offsets = (int*)carve((N_AREA + 1) * 4);
    int* cursor = (int*)carve(N_AREA * 4);
    int2* ew = (int2*)carve(((size_t)E + 4 * N_AREA + 64) * 8);  // padded edge list + over-read tail
    unsigned short* h1 = (unsigned short*)carve((size_t)BATCH * N_AREA * HID * 2);
    unsigned short* h2 = (unsigned short*)carve((size_t)BATCH * N_AREA * HID * 2);
    _Float16* w2f = (_Float16*)carve(4096 * 2);
    _Float16* w3f = (_Float16*)carve(4096 * 2);
    _Float16* wff = (_Float16*)carve(4096 * 2);

    const int GRID = 8 * NCHUNK * (BATCH / 8);  // 10048

    k_zero<<<(N_AREA + 255) / 256, 256, 0, stream>>>(counts, N_AREA);
    k_hist<<<(E + 255) / 256, 256, 0, stream>>>(ei + E, counts, E);
    k_wcvt<<<1, 256, 0, stream>>>(W2, W3, Wf, w2f, w3f, wff);
    k_scan<<<1, 1024, 0, stream>>>(counts, offsets, cursor, dinv, ew);
    k_scatter<<<(E + 255) / 256, 256, 0, stream>>>(ei, dinv, cursor, ew, E);

    k_conv1<<<GRID, 256, 0, stream>>>(state, W1, b1, g1, be1, h1, offsets, ew);
    k_conv<0><<<GRID, 256, 0, stream>>>(h1, w2f, b2, nullptr, nullptr, h1, h2, offsets, ew, nullptr, nullptr);
    k_conv<2><<<GRID, 256, 0, stream>>>(h2, w3f, b3, g3, be3, h1, out, offsets, ew, wff, bf);
}

// Round 14
// 1040.859 us; speedup vs baseline: 1.6931x; 1.0174x over previous
//
#include <hip/hip_runtime.h>
#include <hip/hip_fp16.h>
#include <cstdint>
#include <cstddef>

#define N_AREA 10000
#define N_FEAT 16
#define HID 64
#define BATCH 64
#define EPSL 1e-5f
#define SLOPE 0.01f
#define NCHUNK 157  // ceil(10000/64)

typedef float fv4 __attribute__((ext_vector_type(4)));
typedef _Float16 h4 __attribute__((ext_vector_type(4)));

__device__ __forceinline__ float lrelu(float x) { return x >= 0.f ? x : SLOPE * x; }
__device__ __forceinline__ float tanh_fast(float x) {
    float t = __expf(2.0f * x);  // v_exp_f32 path
    return 1.0f - 2.0f / (t + 1.0f);
}
__device__ __forceinline__ float2 h2f2(unsigned u) {
    return __half22float2(*reinterpret_cast<const __half2*>(&u));
}
__device__ __forceinline__ unsigned f2h2(float a, float b) {
    __half2 h = __floats2half2_rn(a, b);
    return *reinterpret_cast<const unsigned*>(&h);
}
__device__ __forceinline__ h4 pack4(float a, float b, float c, float d) {
    auto p0 = __builtin_amdgcn_cvt_pkrtz(a, b);  // __fp16x2 (layout == _Float16x2)
    auto p1 = __builtin_amdgcn_cvt_pkrtz(c, d);
    h4 r;
    *reinterpret_cast<decltype(p0)*>(&r) = p0;
    *(reinterpret_cast<decltype(p0)*>(&r) + 1) = p1;
    return r;
}

__global__ __launch_bounds__(256) void k_zero(int* p, int n) {
    int i = blockIdx.x * 256 + threadIdx.x;
    if (i < n) p[i] = 0;
}

__global__ __launch_bounds__(256) void k_hist(const int* __restrict__ dst, int* __restrict__ counts, int E) {
    int e = blockIdx.x * 256 + threadIdx.x;
    if (e < E) atomicAdd(&counts[dst[e]], 1);
}

// Pre-pack W2/W3/Wf into fp16 MFMA A-fragment order (A = W^T):
// frag[((mt*4+kk)*64 + lane)*4 + i] = W[16kk + 4(lane>>4) + i][16mt + (lane&15)]
__global__ __launch_bounds__(256) void k_wcvt(const float* __restrict__ Wa, const float* __restrict__ Wb,
                                              const float* __restrict__ Wc, _Float16* __restrict__ fa,
                                              _Float16* __restrict__ fb, _Float16* __restrict__ fc) {
    int t = threadIdx.x;
    int lane = t & 63, pg = t >> 6;
    int g = lane >> 4, q = lane & 15;
    for (int p = pg; p < 16; p += 4) {
        int mt = p >> 2, kk = p & 3;
        int sb = (16 * kk + 4 * g) * HID + 16 * mt + q;
        int dst = (p * 64 + lane) * 4;
        for (int i = 0; i < 4; ++i) {
            fa[dst + i] = (_Float16)Wa[sb + i * HID];
            fb[dst + i] = (_Float16)Wb[sb + i * HID];
            fc[dst + i] = (_Float16)Wc[sb + i * HID];
        }
    }
}

// offsets (exclusive, padded to x4 per node: 1 self-loop + real edges + weight-0 pads),
// dinv, self-loop entry, pad entries, cursor init. Tail: +64 zero edges for chunked loads.
__global__ __launch_bounds__(1024) void k_scan(const int* __restrict__ counts, int* __restrict__ offsets,
                                               int* __restrict__ cursor, float* __restrict__ dinv,
                                               int2* __restrict__ ew) {
    const int PER = 10;
    int t = threadIdx.x;
    int base = t * PER;
    int local[PER];
    int sum = 0;
#pragma unroll
    for (int i = 0; i < PER; ++i) {
        int idx = base + i;
        int c = (idx < N_AREA) ? (((counts[idx] + 1) + 3) & ~3) : 0;  // padded count
        local[i] = sum;
        sum += c;
    }
    __shared__ int part[1024];
    part[t] = sum;
    __syncthreads();
    for (int off = 1; off < 1024; off <<= 1) {
        int v = (t >= off) ? part[t - off] : 0;
        __syncthreads();
        part[t] += v;
        __syncthreads();
    }
    int excl = (t == 0) ? 0 : part[t - 1];
    if (t == 1023) {
        int tot = part[1023];
        offsets[N_AREA] = tot;
        for (int i = 0; i < 64; ++i) ew[tot + i] = make_int2(0, 0);  // safe over-read tail
    }
    for (int i = 0; i < PER; ++i) {
        int idx = base + i;
        if (idx < N_AREA) {
            int off = excl + local[i];
            offsets[idx] = off;
            int c = counts[idx] + 1;          // real count (self + edges)
            int pc = (c + 3) & ~3;            // padded
            float dv = rsqrtf((float)c);
            dinv[idx] = dv;
            ew[off] = make_int2(idx, __float_as_int(dv * dv));  // self loop
            for (int pp = c; pp < pc; ++pp) ew[off + pp] = make_int2(idx, 0);  // weight-0 pads
            cursor[idx] = off + 1;
        }
    }
}

__global__ __launch_bounds__(256) void k_scatter(const int* __restrict__ ei, const float* __restrict__ dinv,
                                                 int* __restrict__ cursor, int2* __restrict__ ew, int E) {
    int e = blockIdx.x * 256 + threadIdx.x;
    if (e < E) {
        int s = ei[e], d = ei[E + e];
        int p = atomicAdd(&cursor[d], 1);
        ew[p] = make_int2(s, __float_as_int(dinv[s] * dinv[d]));
    }
}

// conv1 fused: gather(state rows of 16) -> @W1+b1 -> LN -> leaky -> h1 (fp16) [B][N][64]
__global__ __launch_bounds__(256, 8) void k_conv1(const float* __restrict__ state, const float* __restrict__ W1,
                                                  const float* __restrict__ b1, const float* __restrict__ g1,
                                                  const float* __restrict__ be1, unsigned short* __restrict__ h1,
                                                  const int* __restrict__ offs, const int2* __restrict__ ew) {
    __shared__ float xs[64][20];
    __shared__ float ws[16][64];
    int blk = blockIdx.x;
    int xc = blk & 7, ii = blk >> 3;  // XCD group: batch b on XCD b%8
    int b = xc + 8 * (ii / NCHUNK);
    int c = ii % NCHUNK;
    int n0 = c * 64;
    int t = threadIdx.x;
    *(float4*)&ws[t >> 4][(t & 15) * 4] = *(const float4*)(W1 + (t >> 4) * HID + (t & 15) * 4);
    int ln = t >> 2, q = t & 3;
    int n = n0 + ln;
    const float* sb = state + (size_t)b * (N_AREA * N_FEAT);
    float4 acc = make_float4(0.f, 0.f, 0.f, 0.f);
    if (n < N_AREA) {
        int beg = offs[n], end = offs[n + 1];
        for (int e = beg; e < end; ++e) {
            int2 sw = ew[e];
            float w = __int_as_float(sw.y);
            float4 v = *(const float4*)(sb + (size_t)sw.x * N_FEAT + q * 4);
            acc.x += w * v.x; acc.y += w * v.y; acc.z += w * v.z; acc.w += w * v.w;
        }
    }
    *(float4*)&xs[ln][q * 4] = acc;
    __syncthreads();
    int wave = t >> 6, lane = t & 63;
    float bias = b1[lane], gg = g1[lane], bb = be1[lane];
    for (int j = 0; j < 16; ++j) {
        int lnn = wave * 16 + j;
        float a = bias;
#pragma unroll
        for (int f = 0; f < N_FEAT; ++f) a += xs[lnn][f] * ws[f][lane];
        float s = a;
#pragma unroll
        for (int m = 1; m < 64; m <<= 1) s += __shfl_xor(s, m);
        float mu = s * (1.0f / 64.0f);
        float dv = a - mu;
        float qv = dv * dv;
#pragma unroll
        for (int m = 1; m < 64; m <<= 1) qv += __shfl_xor(qv, m);
        float rstd = rsqrtf(qv * (1.0f / 64.0f) + EPSL);
        float y = lrelu(dv * rstd * gg + bb);
        int nn = n0 + lnn;
        unsigned hv = (unsigned)__half_as_ushort(__float2half_rn(y));
        unsigned ov = (unsigned)__shfl_xor((int)hv, 1);
        if (((lane & 1) == 0) && nn < N_AREA)
            *(unsigned*)(h1 + (size_t)b * (N_AREA * HID) + (size_t)nn * HID + lane) = hv | (ov << 16);
    }
}

// Fused conv: chunked edge gather (LDS-staged chunk + consecutive-edge chains + fma_mix)
//  -> MFMA GEMM1 (out^T = W^T x a^T) -> epilogue.
// Edge chunk staged to per-wave LDS slab (wave-synchronous, no barrier); each lane group q
// consumes consecutive edges 16k+4q+{0..3} via broadcast ds_read (replaces 8 ds_bpermute/superiter).
// Accumulation uses w * (float)h16 -> v_fma_mix_f32 (no explicit cvt).
// a_t layout [feat][node] with granule-XOR swizzle phys(f,c) = 4*((c>>2)^((f>>2)&7)) + (c&3).
// MFMA 16x16x16_f16: A[m=l&15][k=4(l>>4)+i], B[k=4(l>>4)+i][n=l&15], D[m=4(l>>4)+i][n=l&15].
// EPI 0: h2(fp16) = leaky(.+b) + resid
// EPI 2: h3 = leaky(LN(.+b)) + resid; h3 D-frags ARE GEMM2 B-frags (in-register); out = tanh(h3@Wf+bf)
template <int EPI>
__global__ __launch_bounds__(256, 8) void k_conv(const unsigned short* __restrict__ src,
                                                 const _Float16* __restrict__ Wfrag,
                                                 const float* __restrict__ bias, const float* __restrict__ g,
                                                 const float* __restrict__ be, const unsigned short* __restrict__ resid,
                                                 void* __restrict__ out, const int* __restrict__ offs,
                                                 const int2* __restrict__ ew, const _Float16* __restrict__ WfFrag,
                                                 const float* __restrict__ bf) {
    __shared__ float a_t[64][68];
    __shared__ int2 echunk[4][64];  // per-wave edge chunk slab (512 B/wave)
    int blk = blockIdx.x;
    int xc = blk & 7, ii = blk >> 3;
    int b = xc + 8 * (ii / NCHUNK);
    int c = ii % NCHUNK;
    int n0 = c * 64;
    int t = threadIdx.x;
    int lane = t & 63;
    int wave = __builtin_amdgcn_readfirstlane(t) >> 6;  // provably wave-uniform -> scalar offs
    int q = lane >> 4;         // quad group (gather) == k-group g (MFMA)
    int ql = lane & 15;
    int f4 = ql * 4;
    const unsigned short* sp = src + (size_t)b * (N_AREA * HID);
    const _Float16* spH = (const _Float16*)sp;
    int nb = n0 + wave * 16;
    int beg = 0, end = 0;
    if (nb < N_AREA) { beg = offs[nb]; end = offs[nb + 1]; }
    int2 eC = ew[beg + lane];
    for (int j = 0; j < 16; ++j) {
        int n = nb + j;
        int cnt = (n < N_AREA) ? (end - beg) : 0;
        int nbeg = end;
        int nend = (n + 1 < N_AREA) ? offs[n + 2] : end;
        int2 eN = ew[nbeg + lane];
        echunk[wave][lane] = eC;  // stage chunk; wave-synchronous (no barrier needed)
        int cmin = cnt > 64 ? 64 : cnt;
        fv4 a0 = {0.f, 0.f, 0.f, 0.f}, a1 = a0, a2 = a0, a3 = a0;
        int k16 = cmin >> 4;
        for (int k = 0; k < k16; ++k) {
            int e0 = 16 * k + 4 * q;  // uniform within quad group -> broadcast reads
            int2 ea = echunk[wave][e0 + 0];
            int2 eb = echunk[wave][e0 + 1];
            int2 ec = echunk[wave][e0 + 2];
            int2 ed = echunk[wave][e0 + 3];
            h4 va = *(const h4*)(spH + (unsigned)ea.x * HID + f4);
            h4 vb = *(const h4*)(spH + (unsigned)eb.x * HID + f4);
            h4 vc = *(const h4*)(spH + (unsigned)ec.x * HID + f4);
            h4 vd = *(const h4*)(spH + (unsigned)ed.x * HID + f4);
            float wa = __int_as_float(ea.y), wb = __int_as_float(eb.y);
            float wc = __int_as_float(ec.y), wd = __int_as_float(ed.y);
            a0.x += wa * (float)va[0]; a0.y += wa * (float)va[1]; a0.z += wa * (float)va[2]; a0.w += wa * (float)va[3];
            a1.x += wb * (float)vb[0]; a1.y += wb * (float)vb[1]; a1.z += wb * (float)vb[2]; a1.w += wb * (float)vb[3];
            a2.x += wc * (float)vc[0]; a2.y += wc * (float)vc[1]; a2.z += wc * (float)vc[2]; a2.w += wc * (float)vc[3];
            a3.x += wd * (float)vd[0]; a3.y += wd * (float)vd[1]; a3.z += wd * (float)vd[2]; a3.w += wd * (float)vd[3];
        }
        for (int e4 = k16 * 16; e4 < cmin; e4 += 4) {  // padded x4 tail: one edge per quad group
            int2 ea = echunk[wave][e4 + q];
            h4 va = *(const h4*)(spH + (unsigned)ea.x * HID + f4);
            float wa = __int_as_float(ea.y);
            a0.x += wa * (float)va[0]; a0.y += wa * (float)va[1]; a0.z += wa * (float)va[2]; a0.w += wa * (float)va[3];
        }
        if (cnt > 64) {  // rare overflow: direct global quad loads
            for (int e = beg + 64; e < end; e += 4) {
                int2 ea = ew[e + q];
                h4 va = *(const h4*)(spH + (unsigned)ea.x * HID + f4);
                float wa = __int_as_float(ea.y);
                a0.x += wa * (float)va[0]; a0.y += wa * (float)va[1]; a0.z += wa * (float)va[2]; a0.w += wa * (float)va[3];
            }
        }
        fv4 acc = (a0 + a1) + (a2 + a3);
        acc.x += __shfl_xor(acc.x, 16); acc.y += __shfl_xor(acc.y, 16);
        acc.z += __shfl_xor(acc.z, 16); acc.w += __shfl_xor(acc.w, 16);
        acc.x += __shfl_xor(acc.x, 32); acc.y += __shfl_xor(acc.y, 32);
        acc.z += __shfl_xor(acc.z, 32); acc.w += __shfl_xor(acc.w, 32);
        if (q == 0) {
            int ln = wave * 16 + j;
            int colp = 4 * ((ln >> 2) ^ (ql & 7)) + (ln & 3);  // granule-XOR swizzle
            a_t[f4 + 0][colp] = acc.x;
            a_t[f4 + 1][colp] = acc.y;
            a_t[f4 + 2][colp] = acc.z;
            a_t[f4 + 3][colp] = acc.w;
        }
        eC = eN; beg = nbeg; end = nend;
    }
    __syncthreads();
    // ---- MFMA GEMM1: acc[mt] = out^T tile, lane: node nd, feats 16mt+4q+i ----
    fv4 acc[4] = {{0.f, 0.f, 0.f, 0.f}, {0.f, 0.f, 0.f, 0.f}, {0.f, 0.f, 0.f, 0.f}, {0.f, 0.f, 0.f, 0.f}};
#pragma unroll
    for (int kk = 0; kk < 4; ++kk) {
        int f0 = 16 * kk + 4 * q;
        int colp = 4 * ((4 * wave + (ql >> 2)) ^ ((4 * kk + q) & 7)) + (ql & 3);  // inverse swizzle
        float b0 = a_t[f0 + 0][colp];
        float b1 = a_t[f0 + 1][colp];
        float b2 = a_t[f0 + 2][colp];
        float b3 = a_t[f0 + 3][colp];
        h4 bfr = pack4(b0, b1, b2, b3);
#pragma unroll
        for (int mt = 0; mt < 4; ++mt) {
            h4 af = *(const h4*)(Wfrag + ((mt * 4 + kk) * 64 + lane) * 4);
            acc[mt] = __builtin_amdgcn_mfma_f32_16x16x16f16(af, bfr, acc[mt], 0, 0, 0);
        }
    }
    int nd = n0 + 16 * wave + ql;
#pragma unroll
    for (int mt = 0; mt < 4; ++mt) {
        float4 bv = *(const float4*)(bias + 16 * mt + 4 * q);
        acc[mt].x += bv.x; acc[mt].y += bv.y; acc[mt].z += bv.z; acc[mt].w += bv.w;
    }
    if constexpr (EPI >= 1) {  // LayerNorm over 64 feats: per-lane 16 vals + reduce across k-groups
        float s = 0.f, qv = 0.f;
#pragma unroll
        for (int mt = 0; mt < 4; ++mt) {
            s += acc[mt].x + acc[mt].y + acc[mt].z + acc[mt].w;
            qv += acc[mt].x * acc[mt].x + acc[mt].y * acc[mt].y + acc[mt].z * acc[mt].z + acc[mt].w * acc[mt].w;
        }
        s += __shfl_xor(s, 16); s += __shfl_xor(s, 32);
        qv += __shfl_xor(qv, 16); qv += __shfl_xor(qv, 32);
        float mu = s * (1.0f / 64.0f);
        float var = qv * (1.0f / 64.0f) - mu * mu;
        float rstd = rsqrtf(var + EPSL);
#pragma unroll
        for (int mt = 0; mt < 4; ++mt) {
            float4 gv = *(const float4*)(g + 16 * mt + 4 * q);
            float4 bev = *(const float4*)(be + 16 * mt + 4 * q);
            acc[mt].x = (acc[mt].x - mu) * rstd * gv.x + bev.x;
            acc[mt].y = (acc[mt].y - mu) * rstd * gv.y + bev.y;
            acc[mt].z = (acc[mt].z - mu) * rstd * gv.z + bev.z;
            acc[mt].w = (acc[mt].w - mu) * rstd * gv.w + bev.w;
        }
    }
    const unsigned short* rb = resid + (size_t)b * (N_AREA * HID);
    if constexpr (EPI == 0) {
        unsigned short* ob = (unsigned short*)out + (size_t)b * (N_AREA * HID);
        if (nd < N_AREA) {
            size_t rowo = (size_t)nd * HID;
#pragma unroll
            for (int mt = 0; mt < 4; ++mt) {
                int fo = 16 * mt + 4 * q;
                uint2 rr = *(const uint2*)(rb + rowo + fo);
                float2 r01 = h2f2(rr.x), r23 = h2f2(rr.y);
                float o0 = lrelu(acc[mt].x) + r01.x;
                float o1 = lrelu(acc[mt].y) + r01.y;
                float o2 = lrelu(acc[mt].z) + r23.x;
                float o3 = lrelu(acc[mt].w) + r23.y;
                uint2 st;
                st.x = f2h2(o0, o1);
                st.y = f2h2(o2, o3);
                *(uint2*)(ob + rowo + fo) = st;
            }
        }
    } else {  // EPI == 2: finish h3 in-register; D-frags double as GEMM2 B-frags
        int ncl = nd < N_AREA ? nd : (N_AREA - 1);
        size_t rowo = (size_t)ncl * HID;
        h4 h3f[4];
#pragma unroll
        for (int mt = 0; mt < 4; ++mt) {
            int fo = 16 * mt + 4 * q;
            uint2 rr = *(const uint2*)(rb + rowo + fo);
            float2 r01 = h2f2(rr.x), r23 = h2f2(rr.y);
            float v0 = lrelu(acc[mt].x) + r01.x;
            float v1 = lrelu(acc[mt].y) + r01.y;
            float v2 = lrelu(acc[mt].z) + r23.x;
            float v3 = lrelu(acc[mt].w) + r23.y;
            h3f[mt] = pack4(v0, v1, v2, v3);
        }
        fv4 acc2[4] = {{0.f, 0.f, 0.f, 0.f}, {0.f, 0.f, 0.f, 0.f}, {0.f, 0.f, 0.f, 0.f}, {0.f, 0.f, 0.f, 0.f}};
#pragma unroll
        for (int kk = 0; kk < 4; ++kk) {
#pragma unroll
            for (int mt = 0; mt < 4; ++mt) {
                h4 af = *(const h4*)(WfFrag + ((mt * 4 + kk) * 64 + lane) * 4);
                acc2[mt] = __builtin_amdgcn_mfma_f32_16x16x16f16(af, h3f[kk], acc2[mt], 0, 0, 0);
            }
        }
        float* ob = (float*)out + (size_t)b * (N_AREA * HID);
        if (nd < N_AREA) {
#pragma unroll
            for (int mt = 0; mt < 4; ++mt) {
                float4 bfv = *(const float4*)(bf + 16 * mt + 4 * q);
                float4 o;
                o.x = tanh_fast(acc2[mt].x + bfv.x);
                o.y = tanh_fast(acc2[mt].y + bfv.y);
                o.z = tanh_fast(acc2[mt].z + bfv.z);
                o.w = tanh_fast(acc2[mt].w + bfv.w);
                *(float4*)(ob + (size_t)nd * HID + 16 * mt + 4 * q) = o;
            }
        }
    }
}

extern "C" void kernel_launch(void* const* d_in, const int* in_sizes, int n_in,
                              void* d_out, int out_size, void* d_ws, size_t ws_size,
                              hipStream_t stream) {
    const float* state = (const float*)d_in[0];
    const int* ei = (const int*)d_in[1];
    const int E = in_sizes[1] / 2;
    const float* W1 = (const float*)d_in[5];
    const float* b1 = (const float*)d_in[6];
    const float* W2 = (const float*)d_in[7];
    const float* b2 = (const float*)d_in[8];
    const float* W3 = (const float*)d_in[9];
    const float* b3 = (const float*)d_in[10];
    const float* g1 = (const float*)d_in[11];
    const float* be1 = (const float*)d_in[12];
    const float* g3 = (const float*)d_in[13];
    const float* be3 = (const float*)d_in[14];
    const float* Wf = (const float*)d_in[15];
    const float* bf = (const float*)d_in[16];
    float* out = (float*)d_out;

    uint8_t* base = (uint8_t*)d_ws;
    size_t off = 0;
    auto carve = [&](size_t bytes) {
        void* p = base + off;
        off = (off + bytes + 255) & ~(size_t)255;
        return p;
    };
    float* dinv = (float*)carve(N_AREA * 4);
    int* counts = (int*)carve(N_AREA * 4);
    int* offsets = (int*)carve((N_AREA + 1) * 4);
    int* cursor = (int*)carve(N_AREA * 4);
    int2* ew = (int2*)carve(((size_t)E + 4 * N_AREA + 64) * 8);  // padded edge list + over-read tail
    unsigned short* h1 = (unsigned short*)carve((size_t)BATCH * N_AREA * HID * 2);
    unsigned short* h2 = (unsigned short*)carve((size_t)BATCH * N_AREA * HID * 2);
    _Float16* w2f = (_Float16*)carve(4096 * 2);
    _Float16* w3f = (_Float16*)carve(4096 * 2);
    _Float16* wff = (_Float16*)carve(4096 * 2);

    const int GRID = 8 * NCHUNK * (BATCH / 8);  // 10048

    k_zero<<<(N_AREA + 255) / 256, 256, 0, stream>>>(counts, N_AREA);
    k_hist<<<(E + 255) / 256, 256, 0, stream>>>(ei + E, counts, E);
    k_wcvt<<<1, 256, 0, stream>>>(W2, W3, Wf, w2f, w3f, wff);
    k_scan<<<1, 1024, 0, stream>>>(counts, offsets, cursor, dinv, ew);
    k_scatter<<<(E + 255) / 256, 256, 0, stream>>>(ei, dinv, cursor, ew, E);

    k_conv1<<<GRID, 256, 0, stream>>>(state, W1, b1, g1, be1, h1, offsets, ew);
    k_conv<0><<<GRID, 256, 0, stream>>>(h1, w2f, b2, nullptr, nullptr, h1, h2, offsets, ew, nullptr, nullptr);
    k_conv<2><<<GRID, 256, 0, stream>>>(h2, w3f, b3, g3, be3, h1, out, offsets, ew, wff, bf);
}

// Round 16
// 1011.956 us; speedup vs baseline: 1.7415x; 1.0286x over previous
//
#include <hip/hip_runtime.h>
#include <hip/hip_fp16.h>
#include <cstdint>
#include <cstddef>

#define N_AREA 10000
#define N_FEAT 16
#define HID 64
#define BATCH 64
#define EPSL 1e-5f
#define SLOPE 0.01f
#define NCHUNK 157  // ceil(10000/64)

typedef float fv4 __attribute__((ext_vector_type(4)));
typedef _Float16 h4 __attribute__((ext_vector_type(4)));

__device__ __forceinline__ float lrelu(float x) { return x >= 0.f ? x : SLOPE * x; }
__device__ __forceinline__ float tanh_fast(float x) {
    float t = __expf(2.0f * x);  // v_exp_f32 path
    return 1.0f - 2.0f / (t + 1.0f);
}
__device__ __forceinline__ float2 h2f2(unsigned u) {
    return __half22float2(*reinterpret_cast<const __half2*>(&u));
}
__device__ __forceinline__ unsigned f2h2(float a, float b) {
    __half2 h = __floats2half2_rn(a, b);
    return *reinterpret_cast<const unsigned*>(&h);
}
__device__ __forceinline__ h4 pack4(float a, float b, float c, float d) {
    auto p0 = __builtin_amdgcn_cvt_pkrtz(a, b);  // __fp16x2 (layout == _Float16x2)
    auto p1 = __builtin_amdgcn_cvt_pkrtz(c, d);
    h4 r;
    *reinterpret_cast<decltype(p0)*>(&r) = p0;
    *(reinterpret_cast<decltype(p0)*>(&r) + 1) = p1;
    return r;
}

__global__ __launch_bounds__(256) void k_zero(int* p, int n) {
    int i = blockIdx.x * 256 + threadIdx.x;
    if (i < n) p[i] = 0;
}

__global__ __launch_bounds__(256) void k_hist(const int* __restrict__ dst, int* __restrict__ counts, int E) {
    int e = blockIdx.x * 256 + threadIdx.x;
    if (e < E) atomicAdd(&counts[dst[e]], 1);
}

// Pre-pack W2/W3/Wf into fp16 MFMA A-fragment order (A = W^T):
// frag[((mt*4+kk)*64 + lane)*4 + i] = W[16kk + 4(lane>>4) + i][16mt + (lane&15)]
__global__ __launch_bounds__(256) void k_wcvt(const float* __restrict__ Wa, const float* __restrict__ Wb,
                                              const float* __restrict__ Wc, _Float16* __restrict__ fa,
                                              _Float16* __restrict__ fb, _Float16* __restrict__ fc) {
    int t = threadIdx.x;
    int lane = t & 63, pg = t >> 6;
    int g = lane >> 4, q = lane & 15;
    for (int p = pg; p < 16; p += 4) {
        int mt = p >> 2, kk = p & 3;
        int sb = (16 * kk + 4 * g) * HID + 16 * mt + q;
        int dst = (p * 64 + lane) * 4;
        for (int i = 0; i < 4; ++i) {
            fa[dst + i] = (_Float16)Wa[sb + i * HID];
            fb[dst + i] = (_Float16)Wb[sb + i * HID];
            fc[dst + i] = (_Float16)Wc[sb + i * HID];
        }
    }
}

// offsets (exclusive, padded to x8 per node: 1 self-loop + real edges + weight-0 pads),
// dinv, self-loop entry, pad entries, cursor init. Tail: +64 zero edges for chunked loads.
// (x8 padding lets conv1 consume 8 edges/step; k_conv's 4-step tail stays valid: 8 % 4 == 0.)
__global__ __launch_bounds__(1024) void k_scan(const int* __restrict__ counts, int* __restrict__ offsets,
                                               int* __restrict__ cursor, float* __restrict__ dinv,
                                               int2* __restrict__ ew) {
    const int PER = 10;
    int t = threadIdx.x;
    int base = t * PER;
    int local[PER];
    int sum = 0;
#pragma unroll
    for (int i = 0; i < PER; ++i) {
        int idx = base + i;
        int c = (idx < N_AREA) ? (((counts[idx] + 1) + 7) & ~7) : 0;  // padded count (x8)
        local[i] = sum;
        sum += c;
    }
    __shared__ int part[1024];
    part[t] = sum;
    __syncthreads();
    for (int off = 1; off < 1024; off <<= 1) {
        int v = (t >= off) ? part[t - off] : 0;
        __syncthreads();
        part[t] += v;
        __syncthreads();
    }
    int excl = (t == 0) ? 0 : part[t - 1];
    if (t == 1023) {
        int tot = part[1023];
        offsets[N_AREA] = tot;
        for (int i = 0; i < 64; ++i) ew[tot + i] = make_int2(0, 0);  // safe over-read tail
    }
    for (int i = 0; i < PER; ++i) {
        int idx = base + i;
        if (idx < N_AREA) {
            int off = excl + local[i];
            offsets[idx] = off;
            int c = counts[idx] + 1;          // real count (self + edges)
            int pc = (c + 7) & ~7;            // padded x8
            float dv = rsqrtf((float)c);
            dinv[idx] = dv;
            ew[off] = make_int2(idx, __float_as_int(dv * dv));  // self loop
            for (int pp = c; pp < pc; ++pp) ew[off + pp] = make_int2(idx, 0);  // weight-0 pads
            cursor[idx] = off + 1;
        }
    }
}

__global__ __launch_bounds__(256) void k_scatter(const int* __restrict__ ei, const float* __restrict__ dinv,
                                                 int* __restrict__ cursor, int2* __restrict__ ew, int E) {
    int e = blockIdx.x * 256 + threadIdx.x;
    if (e < E) {
        int s = ei[e], d = ei[E + e];
        int p = atomicAdd(&cursor[d], 1);
        ew[p] = make_int2(s, __float_as_int(dinv[s] * dinv[d]));
    }
}

// conv1 fused: CHUNKED gather (R6/R14-verified pattern; 8-lane float2 rows, 8 edges/VMEM instr)
//  -> @W1+b1 -> LN -> leaky -> h1 (fp16) [B][N][64]
__global__ __launch_bounds__(256, 8) void k_conv1(const float* __restrict__ state, const float* __restrict__ W1,
                                                  const float* __restrict__ b1, const float* __restrict__ g1,
                                                  const float* __restrict__ be1, unsigned short* __restrict__ h1,
                                                  const int* __restrict__ offs, const int2* __restrict__ ew) {
    __shared__ float xs[64][20];
    __shared__ float ws[16][64];
    __shared__ int2 echunk1[4][64];
    int blk = blockIdx.x;
    int xc = blk & 7, ii = blk >> 3;  // XCD group: batch b on XCD b%8
    int b = xc + 8 * (ii / NCHUNK);
    int c = ii % NCHUNK;
    int n0 = c * 64;
    int t = threadIdx.x;
    *(float4*)&ws[t >> 4][(t & 15) * 4] = *(const float4*)(W1 + (t >> 4) * HID + (t & 15) * 4);
    int lane = t & 63;
    int wave = __builtin_amdgcn_readfirstlane(t) >> 6;  // wave-uniform -> scalar offs
    int q8 = lane >> 3;   // edge group 0..7
    int f2 = lane & 7;    // float2 slot within 16-float row
    const float2* s2 = (const float2*)(state + (size_t)b * (N_AREA * N_FEAT));
    int nb = n0 + wave * 16;
    int beg = 0, end = 0;
    if (nb < N_AREA) { beg = offs[nb]; end = offs[nb + 1]; }
    int2 eC = ew[beg + lane];
    for (int j = 0; j < 16; ++j) {
        int n = nb + j;
        int cnt = (n < N_AREA) ? (end - beg) : 0;
        int nbeg = end;
        int nend = (n + 1 < N_AREA) ? offs[n + 2] : end;
        int2 eN = ew[nbeg + lane];
        echunk1[wave][lane] = eC;  // wave-synchronous stage
        int cmin = cnt > 64 ? 64 : cnt;
        float2 a0 = make_float2(0.f, 0.f), a1 = a0;
        int k16 = cmin >> 4;
        for (int k = 0; k < k16; ++k) {  // 16 edges: 2 chains x 8 groups
            int2 ea = echunk1[wave][16 * k + q8];
            int2 eb = echunk1[wave][16 * k + 8 + q8];
            float2 va = s2[(unsigned)ea.x * 8 + f2];
            float2 vb = s2[(unsigned)eb.x * 8 + f2];
            float wa = __int_as_float(ea.y), wb = __int_as_float(eb.y);
            a0.x += wa * va.x; a0.y += wa * va.y;
            a1.x += wb * vb.x; a1.y += wb * vb.y;
        }
        for (int e8 = k16 * 16; e8 < cmin; e8 += 8) {  // padded x8 tail
            int2 ea = echunk1[wave][e8 + q8];
            float2 va = s2[(unsigned)ea.x * 8 + f2];
            float wa = __int_as_float(ea.y);
            a0.x += wa * va.x; a0.y += wa * va.y;
        }
        if (cnt > 64) {  // rare overflow: direct loads (count x8-padded)
            for (int e = beg + 64; e < end; e += 8) {
                int2 ea = ew[e + q8];
                float2 va = s2[(unsigned)ea.x * 8 + f2];
                float wa = __int_as_float(ea.y);
                a0.x += wa * va.x; a0.y += wa * va.y;
            }
        }
        float2 acc = make_float2(a0.x + a1.x, a0.y + a1.y);
        acc.x += __shfl_xor(acc.x, 8);  acc.y += __shfl_xor(acc.y, 8);
        acc.x += __shfl_xor(acc.x, 16); acc.y += __shfl_xor(acc.y, 16);
        acc.x += __shfl_xor(acc.x, 32); acc.y += __shfl_xor(acc.y, 32);
        if (q8 == 0) {
            int ln = wave * 16 + j;
            xs[ln][f2 * 2 + 0] = acc.x;
            xs[ln][f2 * 2 + 1] = acc.y;
        }
        eC = eN; beg = nbeg; end = nend;
    }
    __syncthreads();
    float bias = b1[lane], gg = g1[lane], bb = be1[lane];
    for (int j = 0; j < 16; ++j) {
        int lnn = wave * 16 + j;
        float a = bias;
#pragma unroll
        for (int f = 0; f < N_FEAT; ++f) a += xs[lnn][f] * ws[f][lane];
        float s = a;
#pragma unroll
        for (int m = 1; m < 64; m <<= 1) s += __shfl_xor(s, m);
        float mu = s * (1.0f / 64.0f);
        float dv = a - mu;
        float qv = dv * dv;
#pragma unroll
        for (int m = 1; m < 64; m <<= 1) qv += __shfl_xor(qv, m);
        float rstd = rsqrtf(qv * (1.0f / 64.0f) + EPSL);
        float y = lrelu(dv * rstd * gg + bb);
        int nn = n0 + lnn;
        unsigned hv = (unsigned)__half_as_ushort(__float2half_rn(y));
        unsigned ov = (unsigned)__shfl_xor((int)hv, 1);
        if (((lane & 1) == 0) && nn < N_AREA)
            *(unsigned*)(h1 + (size_t)b * (N_AREA * HID) + (size_t)nn * HID + lane) = hv | (ov << 16);
    }
}

// Fused conv: chunked edge gather (LDS-staged chunk + consecutive-edge chains + fma_mix)
//  -> MFMA GEMM1 (out^T = W^T x a^T) -> epilogue. [UNCHANGED from round 14 — at fp16 line wall]
// EPI 0: h2(fp16) = leaky(.+b) + resid
// EPI 2: h3 = leaky(LN(.+b)) + resid; h3 D-frags ARE GEMM2 B-frags (in-register); out = tanh(h3@Wf+bf)
template <int EPI>
__global__ __launch_bounds__(256, 8) void k_conv(const unsigned short* __restrict__ src,
                                                 const _Float16* __restrict__ Wfrag,
                                                 const float* __restrict__ bias, const float* __restrict__ g,
                                                 const float* __restrict__ be, const unsigned short* __restrict__ resid,
                                                 void* __restrict__ out, const int* __restrict__ offs,
                                                 const int2* __restrict__ ew, const _Float16* __restrict__ WfFrag,
                                                 const float* __restrict__ bf) {
    __shared__ float a_t[64][68];
    __shared__ int2 echunk[4][64];  // per-wave edge chunk slab (512 B/wave)
    int blk = blockIdx.x;
    int xc = blk & 7, ii = blk >> 3;
    int b = xc + 8 * (ii / NCHUNK);
    int c = ii % NCHUNK;
    int n0 = c * 64;
    int t = threadIdx.x;
    int lane = t & 63;
    int wave = __builtin_amdgcn_readfirstlane(t) >> 6;  // provably wave-uniform -> scalar offs
    int q = lane >> 4;         // quad group (gather) == k-group g (MFMA)
    int ql = lane & 15;
    int f4 = ql * 4;
    const unsigned short* sp = src + (size_t)b * (N_AREA * HID);
    const _Float16* spH = (const _Float16*)sp;
    int nb = n0 + wave * 16;
    int beg = 0, end = 0;
    if (nb < N_AREA) { beg = offs[nb]; end = offs[nb + 1]; }
    int2 eC = ew[beg + lane];
    for (int j = 0; j < 16; ++j) {
        int n = nb + j;
        int cnt = (n < N_AREA) ? (end - beg) : 0;
        int nbeg = end;
        int nend = (n + 1 < N_AREA) ? offs[n + 2] : end;
        int2 eN = ew[nbeg + lane];
        echunk[wave][lane] = eC;  // stage chunk; wave-synchronous (no barrier needed)
        int cmin = cnt > 64 ? 64 : cnt;
        fv4 a0 = {0.f, 0.f, 0.f, 0.f}, a1 = a0, a2 = a0, a3 = a0;
        int k16 = cmin >> 4;
        for (int k = 0; k < k16; ++k) {
            int e0 = 16 * k + 4 * q;  // uniform within quad group -> broadcast reads
            int2 ea = echunk[wave][e0 + 0];
            int2 eb = echunk[wave][e0 + 1];
            int2 ec = echunk[wave][e0 + 2];
            int2 ed = echunk[wave][e0 + 3];
            h4 va = *(const h4*)(spH + (unsigned)ea.x * HID + f4);
            h4 vb = *(const h4*)(spH + (unsigned)eb.x * HID + f4);
            h4 vc = *(const h4*)(spH + (unsigned)ec.x * HID + f4);
            h4 vd = *(const h4*)(spH + (unsigned)ed.x * HID + f4);
            float wa = __int_as_float(ea.y), wb = __int_as_float(eb.y);
            float wc = __int_as_float(ec.y), wd = __int_as_float(ed.y);
            a0.x += wa * (float)va[0]; a0.y += wa * (float)va[1]; a0.z += wa * (float)va[2]; a0.w += wa * (float)va[3];
            a1.x += wb * (float)vb[0]; a1.y += wb * (float)vb[1]; a1.z += wb * (float)vb[2]; a1.w += wb * (float)vb[3];
            a2.x += wc * (float)vc[0]; a2.y += wc * (float)vc[1]; a2.z += wc * (float)vc[2]; a2.w += wc * (float)vc[3];
            a3.x += wd * (float)vd[0]; a3.y += wd * (float)vd[1]; a3.z += wd * (float)vd[2]; a3.w += wd * (float)vd[3];
        }
        for (int e4 = k16 * 16; e4 < cmin; e4 += 4) {  // padded x4 tail: one edge per quad group
            int2 ea = echunk[wave][e4 + q];
            h4 va = *(const h4*)(spH + (unsigned)ea.x * HID + f4);
            float wa = __int_as_float(ea.y);
            a0.x += wa * (float)va[0]; a0.y += wa * (float)va[1]; a0.z += wa * (float)va[2]; a0.w += wa * (float)va[3];
        }
        if (cnt > 64) {  // rare overflow: direct global quad loads
            for (int e = beg + 64; e < end; e += 4) {
                int2 ea = ew[e + q];
                h4 va = *(const h4*)(spH + (unsigned)ea.x * HID + f4);
                float wa = __int_as_float(ea.y);
                a0.x += wa * (float)va[0]; a0.y += wa * (float)va[1]; a0.z += wa * (float)va[2]; a0.w += wa * (float)va[3];
            }
        }
        fv4 acc = (a0 + a1) + (a2 + a3);
        acc.x += __shfl_xor(acc.x, 16); acc.y += __shfl_xor(acc.y, 16);
        acc.z += __shfl_xor(acc.z, 16); acc.w += __shfl_xor(acc.w, 16);
        acc.x += __shfl_xor(acc.x, 32); acc.y += __shfl_xor(acc.y, 32);
        acc.z += __shfl_xor(acc.z, 32); acc.w += __shfl_xor(acc.w, 32);
        if (q == 0) {
            int ln = wave * 16 + j;
            int colp = 4 * ((ln >> 2) ^ (ql & 7)) + (ln & 3);  // granule-XOR swizzle
            a_t[f4 + 0][colp] = acc.x;
            a_t[f4 + 1][colp] = acc.y;
            a_t[f4 + 2][colp] = acc.z;
            a_t[f4 + 3][colp] = acc.w;
        }
        eC = eN; beg = nbeg; end = nend;
    }
    __syncthreads();
    // ---- MFMA GEMM1: acc[mt] = out^T tile, lane: node nd, feats 16mt+4q+i ----
    fv4 acc[4] = {{0.f, 0.f, 0.f, 0.f}, {0.f, 0.f, 0.f, 0.f}, {0.f, 0.f, 0.f, 0.f}, {0.f, 0.f, 0.f, 0.f}};
#pragma unroll
    for (int kk = 0; kk < 4; ++kk) {
        int f0 = 16 * kk + 4 * q;
        int colp = 4 * ((4 * wave + (ql >> 2)) ^ ((4 * kk + q) & 7)) + (ql & 3);  // inverse swizzle
        float b0 = a_t[f0 + 0][colp];
        float b1 = a_t[f0 + 1][colp];
        float b2 = a_t[f0 + 2][colp];
        float b3 = a_t[f0 + 3][colp];
        h4 bfr = pack4(b0, b1, b2, b3);
#pragma unroll
        for (int mt = 0; mt < 4; ++mt) {
            h4 af = *(const h4*)(Wfrag + ((mt * 4 + kk) * 64 + lane) * 4);
            acc[mt] = __builtin_amdgcn_mfma_f32_16x16x16f16(af, bfr, acc[mt], 0, 0, 0);
        }
    }
    int nd = n0 + 16 * wave + ql;
#pragma unroll
    for (int mt = 0; mt < 4; ++mt) {
        float4 bv = *(const float4*)(bias + 16 * mt + 4 * q);
        acc[mt].x += bv.x; acc[mt].y += bv.y; acc[mt].z += bv.z; acc[mt].w += bv.w;
    }
    if constexpr (EPI >= 1) {  // LayerNorm over 64 feats: per-lane 16 vals + reduce across k-groups
        float s = 0.f, qv = 0.f;
#pragma unroll
        for (int mt = 0; mt < 4; ++mt) {
            s += acc[mt].x + acc[mt].y + acc[mt].z + acc[mt].w;
            qv += acc[mt].x * acc[mt].x + acc[mt].y * acc[mt].y + acc[mt].z * acc[mt].z + acc[mt].w * acc[mt].w;
        }
        s += __shfl_xor(s, 16); s += __shfl_xor(s, 32);
        qv += __shfl_xor(qv, 16); qv += __shfl_xor(qv, 32);
        float mu = s * (1.0f / 64.0f);
        float var = qv * (1.0f / 64.0f) - mu * mu;
        float rstd = rsqrtf(var + EPSL);
#pragma unroll
        for (int mt = 0; mt < 4; ++mt) {
            float4 gv = *(const float4*)(g + 16 * mt + 4 * q);
            float4 bev = *(const float4*)(be + 16 * mt + 4 * q);
            acc[mt].x = (acc[mt].x - mu) * rstd * gv.x + bev.x;
            acc[mt].y = (acc[mt].y - mu) * rstd * gv.y + bev.y;
            acc[mt].z = (acc[mt].z - mu) * rstd * gv.z + bev.z;
            acc[mt].w = (acc[mt].w - mu) * rstd * gv.w + bev.w;
        }
    }
    const unsigned short* rb = resid + (size_t)b * (N_AREA * HID);
    if constexpr (EPI == 0) {
        unsigned short* ob = (unsigned short*)out + (size_t)b * (N_AREA * HID);
        if (nd < N_AREA) {
            size_t rowo = (size_t)nd * HID;
#pragma unroll
            for (int mt = 0; mt < 4; ++mt) {
                int fo = 16 * mt + 4 * q;
                uint2 rr = *(const uint2*)(rb + rowo + fo);
                float2 r01 = h2f2(rr.x), r23 = h2f2(rr.y);
                float o0 = lrelu(acc[mt].x) + r01.x;
                float o1 = lrelu(acc[mt].y) + r01.y;
                float o2 = lrelu(acc[mt].z) + r23.x;
                float o3 = lrelu(acc[mt].w) + r23.y;
                uint2 st;
                st.x = f2h2(o0, o1);
                st.y = f2h2(o2, o3);
                *(uint2*)(ob + rowo + fo) = st;
            }
        }
    } else {  // EPI == 2: finish h3 in-register; D-frags double as GEMM2 B-frags
        int ncl = nd < N_AREA ? nd : (N_AREA - 1);
        size_t rowo = (size_t)ncl * HID;
        h4 h3f[4];
#pragma unroll
        for (int mt = 0; mt < 4; ++mt) {
            int fo = 16 * mt + 4 * q;
            uint2 rr = *(const uint2*)(rb + rowo + fo);
            float2 r01 = h2f2(rr.x), r23 = h2f2(rr.y);
            float v0 = lrelu(acc[mt].x) + r01.x;
            float v1 = lrelu(acc[mt].y) + r01.y;
            float v2 = lrelu(acc[mt].z) + r23.x;
            float v3 = lrelu(acc[mt].w) + r23.y;
            h3f[mt] = pack4(v0, v1, v2, v3);
        }
        fv4 acc2[4] = {{0.f, 0.f, 0.f, 0.f}, {0.f, 0.f, 0.f, 0.f}, {0.f, 0.f, 0.f, 0.f}, {0.f, 0.f, 0.f, 0.f}};
#pragma unroll
        for (int kk = 0; kk < 4; ++kk) {
#pragma unroll
            for (int mt = 0; mt < 4; ++mt) {
                h4 af = *(const h4*)(WfFrag + ((mt * 4 + kk) * 64 + lane) * 4);
                acc2[mt] = __builtin_amdgcn_mfma_f32_16x16x16f16(af, h3f[kk], acc2[mt], 0, 0, 0);
            }
        }
        float* ob = (float*)out + (size_t)b * (N_AREA * HID);
        if (nd < N_AREA) {
#pragma unroll
            for (int mt = 0; mt < 4; ++mt) {
                float4 bfv = *(const float4*)(bf + 16 * mt + 4 * q);
                float4 o;
                o.x = tanh_fast(acc2[mt].x + bfv.x);
                o.y = tanh_fast(acc2[mt].y + bfv.y);
                o.z = tanh_fast(acc2[mt].z + bfv.z);
                o.w = tanh_fast(acc2[mt].w + bfv.w);
                *(float4*)(ob + (size_t)nd * HID + 16 * mt + 4 * q) = o;
            }
        }
    }
}

extern "C" void kernel_launch(void* const* d_in, const int* in_sizes, int n_in,
                              void* d_out, int out_size, void* d_ws, size_t ws_size,
                              hipStream_t stream) {
    const float* state = (const float*)d_in[0];
    const int* ei = (const int*)d_in[1];
    const int E = in_sizes[1] / 2;
    const float* W1 = (const float*)d_in[5];
    const float* b1 = (const float*)d_in[6];
    const float* W2 = (const float*)d_in[7];
    const float* b2 = (const float*)d_in[8];
    const float* W3 = (const float*)d_in[9];
    const float* b3 = (const float*)d_in[10];
    const float* g1 = (const float*)d_in[11];
    const float* be1 = (const float*)d_in[12];
    const float* g3 = (const float*)d_in[13];
    const float* be3 = (const float*)d_in[14];
    const float* Wf = (const float*)d_in[15];
    const float* bf = (const float*)d_in[16];
    float* out = (float*)d_out;

    uint8_t* base = (uint8_t*)d_ws;
    size_t off = 0;
    auto carve = [&](size_t bytes) {
        void* p = base + off;
        off = (off + bytes + 255) & ~(size_t)255;
        return p;
    };
    float* dinv = (float*)carve(N_AREA * 4);
    int* counts = (int*)carve(N_AREA * 4);
    int* offsets = (int*)carve((N_AREA + 1) * 4);
    int* cursor = (int*)carve(N_AREA * 4);
    int2* ew = (int2*)carve(((size_t)E + 8 * N_AREA + 64) * 8);  // x8-padded edge list + over-read tail
    unsigned short* h1 = (unsigned short*)carve((size_t)BATCH * N_AREA * HID * 2);
    unsigned short* h2 = (unsigned short*)carve((size_t)BATCH * N_AREA * HID * 2);
    _Float16* w2f = (_Float16*)carve(4096 * 2);
    _Float16* w3f = (_Float16*)carve(4096 * 2);
    _Float16* wff = (_Float16*)carve(4096 * 2);

    const int GRID = 8 * NCHUNK * (BATCH / 8);  // 10048

    k_zero<<<(N_AREA + 255) / 256, 256, 0, stream>>>(counts, N_AREA);
    k_hist<<<(E + 255) / 256, 256, 0, stream>>>(ei + E, counts, E);
    k_wcvt<<<1, 256, 0, stream>>>(W2, W3, Wf, w2f, w3f, wff);
    k_scan<<<1, 1024, 0, stream>>>(counts, offsets, cursor, dinv, ew);
    k_scatter<<<(E + 255) / 256, 256, 0, stream>>>(ei, dinv, cursor, ew, E);

    k_conv1<<<GRID, 256, 0, stream>>>(state, W1, b1, g1, be1, h1, offsets, ew);
    k_conv<0><<<GRID, 256, 0, stream>>>(h1, w2f, b2, nullptr, nullptr, h1, h2, offsets, ew, nullptr, nullptr);
    k_conv<2><<<GRID, 256, 0, stream>>>(h2, w3f, b3, g3, be3, h1, out, offsets, ew, wff, bf);
}